// Round 1
// 561.710 us; speedup vs baseline: 1.0672x; 1.0672x over previous
//
#include <hip/hip_runtime.h>
#include <hip/hip_bf16.h>
#include <stdint.h>

typedef __bf16 bf16;
typedef __bf16 bf16x8 __attribute__((ext_vector_type(8)));
typedef __bf16 bf16x4 __attribute__((ext_vector_type(4)));
typedef float f32x4 __attribute__((ext_vector_type(4)));

#define AS1 __attribute__((address_space(1)))
#define AS3 __attribute__((address_space(3)))

// B=4, S=256, H=12, DH=64(pad 128), D=768, FD=2048, FU=2048
// Inputs fp32 + int32 mask. OUTPUT fp32.
// R19: nsplit 8->4 halved C traffic at gs=6.
// R20 (this round): final GEMM was grid-limited to 2 blocks/CU (Occupancy
// 20.6%, MfmaUtil 25.6%, HBM 25% -> latency-bound, not HBM-bound).
//   (a) gs=12: single final GEMM K=33792, nsplit=8 -> 1024 blocks = 4/CU,
//       and no mode-3 C re-read pass.
//   (b) T1 bijective XCD swizzle in gemm_bt (chunk along M: same-XCD blocks
//       share B panels) to cut L2-miss refetch (185MB vs 104MB unique).
//   (c) merge E1+G_t (2x 192-block underfilled dispatches) into one z=24
//       dispatch via pointer-diff batch strides; bf16 mask; float4 casts.

__device__ __forceinline__ void gld16(const bf16* g, bf16* l) {
  __builtin_amdgcn_global_load_lds((AS1 void*)g, (AS3 void*)l, 16, 0, 0);
}

__global__ void k_sentinel(float* __restrict__ out) {
  int i = blockIdx.x * 256 + threadIdx.x;
  if (i < 2097152) out[i] = 1048576.0f;
}

// ---------------- prep kernels ----------------

__global__ void k_invln(const float* __restrict__ ln, float* __restrict__ invln) {
  int i = blockIdx.x * 256 + threadIdx.x;
  if (i < 1024) invln[i] = 1.0f / ln[i];
}

// vectorized fp32 -> bf16 cast, n4 = n/4
__global__ void k_cast4(const float* __restrict__ s, bf16* __restrict__ d, int n4) {
  int i = blockIdx.x * 256 + threadIdx.x;
  if (i < n4) {
    float4 v = *(const float4*)(s + (long)i * 4);
    bf16x4 o;
    o[0] = (bf16)v.x; o[1] = (bf16)v.y; o[2] = (bf16)v.z; o[3] = (bf16)v.w;
    *(bf16x4*)(d + (long)i * 4) = o;
  }
}

// int32 0/1 mask -> bf16, n4 = n/4
__global__ void k_maskb(const int* __restrict__ m, bf16* __restrict__ d, int n4) {
  int i = blockIdx.x * 256 + threadIdx.x;
  if (i < n4) {
    int4 v = *(const int4*)(m + (long)i * 4);
    bf16x4 o;
    o[0] = (bf16)(float)v.x; o[1] = (bf16)(float)v.y;
    o[2] = (bf16)(float)v.z; o[3] = (bf16)(float)v.w;
    *(bf16x4*)(d + (long)i * 4) = o;
  }
}

__global__ void k_WO(const float* __restrict__ W_O, bf16* __restrict__ WOb) {
  int i = blockIdx.x * 256 + threadIdx.x;           // 12*128*768
  int o = i % 768, r = (i / 768) & 127, h = i / (768 * 128);
  WOb[i] = (r < 64) ? (bf16)W_O[(long)(h * 64 + r) * 768 + o] : (bf16)0.0f;
}

__global__ void k_WV(const float* __restrict__ W_V, bf16* __restrict__ WVb) {
  int i = blockIdx.x * 256 + threadIdx.x;           // 12*768*128
  int k = i & 127, m = (i / 128) % 768, h = i / (128 * 768);
  WVb[i] = (k < 64) ? (bf16)W_V[(long)(h * 768 + m) * 64 + k] : (bf16)0.0f;
}

// WVt[h][k<128][i<768] = W_V[h,i,k]  (tiled transpose, zero-pad k>=64)
__global__ void k_WVtT(const float* __restrict__ wv, bf16* __restrict__ WVt) {
  __shared__ float tile[32][33];
  int h = blockIdx.z;                 // 12
  int k0 = blockIdx.x * 32;           // 0..96
  int i0 = blockIdx.y * 32;           // 24 tiles
  int lane = threadIdx.x & 31, rg = threadIdx.x >> 5;
  if (k0 < 64) {
    for (int r = rg; r < 32; r += 8)
      tile[r][lane] = wv[((long)(h * 768 + i0 + r)) * 64 + k0 + lane];
    __syncthreads();
    for (int r = rg; r < 32; r += 8)
      WVt[((long)h * 128 + k0 + r) * 768 + i0 + lane] = (bf16)tile[lane][r];
  } else {
    for (int r = rg; r < 32; r += 8)
      WVt[((long)h * 128 + k0 + r) * 768 + i0 + lane] = (bf16)0.0f;
  }
}

// updWt[u][i] = up_dec_W[i][u]  (tiled transpose)
__global__ void k_updWtT(const float* __restrict__ u, bf16* __restrict__ d) {
  __shared__ float tile[32][33];
  int u0 = blockIdx.x * 32;           // 64 tiles
  int i0 = blockIdx.y * 32;           // 24 tiles
  int lane = threadIdx.x & 31, rg = threadIdx.x >> 5;
  for (int r = rg; r < 32; r += 8)
    tile[r][lane] = u[((long)(i0 + r)) * 2048 + u0 + lane];
  __syncthreads();
  for (int r = rg; r < 32; r += 8)
    d[((long)(u0 + r)) * 768 + i0 + lane] = (bf16)tile[lane][r];
}

// Xt[b][d][s] = resid[b,s,d] * invln  (tiled transpose)
__global__ void k_XtT(const float* __restrict__ resid, const float* __restrict__ invln,
                      bf16* __restrict__ Xt) {
  __shared__ float tile[32][33];
  int b = blockIdx.z, d0 = blockIdx.x * 32, s0 = blockIdx.y * 32;  // (24, 8, 4)
  int lane = threadIdx.x & 31, rg = threadIdx.x >> 5;
  for (int r = rg; r < 32; r += 8) {
    int s = s0 + r;
    tile[r][lane] = resid[((long)(b * 256 + s)) * 768 + d0 + lane] * invln[b * 256 + s];
  }
  __syncthreads();
  for (int r = rg; r < 32; r += 8)
    Xt[((long)b * 768 + d0 + r) * 256 + s0 + lane] = (bf16)tile[lane][r];
}

// Ut[b][u][s] = pruned[b,s,u] * invln  (tiled transpose)
__global__ void k_UtT(const float* __restrict__ pr, const float* __restrict__ invln,
                      bf16* __restrict__ Ut) {
  __shared__ float tile[32][33];
  int b = blockIdx.z, u0 = blockIdx.x * 32, s0 = blockIdx.y * 32;  // (64, 8, 4)
  int lane = threadIdx.x & 31, rg = threadIdx.x >> 5;
  for (int r = rg; r < 32; r += 8) {
    int s = s0 + r;
    tile[r][lane] = pr[((long)(b * 256 + s)) * 2048 + u0 + lane] * invln[b * 256 + s];
  }
  __syncthreads();
  for (int r = rg; r < 32; r += 8)
    Ut[((long)b * 2048 + u0 + r) * 256 + s0 + lane] = (bf16)tile[lane][r];
}

// ---------------- bias chain (fp32, block-parallel) ----------------

__device__ __forceinline__ float blk_reduce(float s) {
  __shared__ float red[256];
  red[threadIdx.x] = s; __syncthreads();
  for (int o = 128; o > 0; o >>= 1) {
    if ((int)threadIdx.x < o) red[threadIdx.x] += red[threadIdx.x + o];
    __syncthreads();
  }
  float r = red[0]; __syncthreads();
  return r;
}

__global__ void k_bias_t(const float* __restrict__ W_V, const float* __restrict__ up_b,
                         float* __restrict__ t_hk) {
  int j = blockIdx.x, h = j >> 6, k = j & 63;
  float s = 0.f;
  for (int m = threadIdx.x; m < 768; m += 256)
    s += W_V[((long)(h * 768 + m)) * 64 + k] * up_b[m];
  float r = blk_reduce(s);
  if (threadIdx.x == 0) t_hk[j] = r;
}

__global__ void k_bias_w(const float* __restrict__ W_O, const float* __restrict__ t_hk,
                         float* __restrict__ w) {
  int d = blockIdx.x;
  float s = 0.f;
  for (int j = threadIdx.x; j < 768; j += 256)
    s += W_O[(long)j * 768 + d] * t_hk[j];
  float r = blk_reduce(s);
  if (threadIdx.x == 0) w[d] = r;
}

__global__ void k_bias_c(const float* __restrict__ enc_W, const float* __restrict__ enc_b,
                         const float* __restrict__ b_dec, const float* __restrict__ w,
                         float* __restrict__ c0, float* __restrict__ c1) {
  int f = blockIdx.x;
  float s0 = 0.f, s1 = 0.f;
  for (int d = threadIdx.x; d < 768; d += 256) {
    float e = enc_W[(long)f * 768 + d];
    s0 += e * b_dec[d];
    s1 += e * w[d];
  }
  float r0 = blk_reduce(s0);
  float r1 = blk_reduce(s1);
  if (threadIdx.x == 0) { c0[f] = enc_b[f] - r0; c1[f] = r1; }
}

// ---------------- GEMM (BT form: C[m,n] = sum_k A[m,k]*B[n,k]) ----------------
// BK=64, XOR-swizzled staging. K (and kChunk) must be multiples of 64.
// mode 0: bf16 store; mode 1: *= bf16 mask, bf16 store;
// mode 2: split-K fp32 overwrite; mode 3: split-K fp32 read-accumulate
__global__ __launch_bounds__(256)
void gemm_bt(const bf16* __restrict__ A, const bf16* __restrict__ B, void* __restrict__ Cv,
             int M, int N, int K,
             long lda, long ldb, long ldc,
             int batchH,
             long sa_b, long sa_h, long sb_b, long sb_h, long sc_b, long sc_h,
             int mode, int kChunk,
             const bf16* __restrict__ mask, long mask_ld)
{
  __shared__ __align__(16) bf16 Asm[128 * 64];
  __shared__ __align__(16) bf16 Bsm[128 * 64];

  const int t = threadIdx.x;

  // T1: bijective XCD-aware remap of the (x,y) tile id (m204 formula).
  // Decode M-fastest so each XCD's contiguous chunk spans full M columns
  // (shares B panels within the XCD's private L2).
  const int nbx = gridDim.x, nby = gridDim.y;
  const int nxy = nbx * nby;
  {
  }
  int orig = blockIdx.x + nbx * blockIdx.y;
  int qq = nxy >> 3, rr = nxy & 7;
  int xcd = orig & 7, lid = orig >> 3;
  int swz = (xcd < rr) ? (xcd * (qq + 1) + lid)
                       : (rr * (qq + 1) + (xcd - rr) * qq + lid);
  const int m0 = (swz % nby) * 128;
  const int n0 = (swz / nby) * 128;

  long aoff, boff, coff;
  int k0, k1;
  if (mode >= 2) {
    int z = blockIdx.z;
    aoff = 0; boff = 0;
    coff = (long)z * (long)M * ldc;
    k0 = z * kChunk; k1 = k0 + kChunk; if (k1 > K) k1 = K;
  } else {
    int z = blockIdx.z;
    int bb = z / batchH, hh = z - bb * batchH;
    aoff = (long)bb * sa_b + (long)hh * sa_h;
    boff = (long)bb * sb_b + (long)hh * sb_h;
    coff = (long)bb * sc_b + (long)hh * sc_h;
    k0 = 0; k1 = K;
  }

  const bf16* Ab = A + aoff + (long)m0 * lda;
  const bf16* Bb = B + boff + (long)n0 * ldb;

  const int r0 = t >> 3;           // 0..31 (staging row within 32-row group)
  const int g8 = t & 7;            // staging col-group (LDS slot)

  const int L = t & 63, w = t >> 6;
  const int wm = (w & 1) * 64, wn = (w >> 1) * 64;
  const int r16 = L & 15, q = L >> 4;

  f32x4 acc[4][4];
#pragma unroll
  for (int i = 0; i < 4; i++)
#pragma unroll
    for (int j = 0; j < 4; j++) acc[i][j] = (f32x4){0.f, 0.f, 0.f, 0.f};

  for (int kt = k0; kt < k1; kt += 64) {
#pragma unroll
    for (int j = 0; j < 4; j++) {
      int row = j * 32 + r0;
      int sc = ((g8 ^ (row & 7)) << 3);      // source col swizzle
      gld16(Ab + (long)row * lda + (kt + sc), &Asm[j * 2048 + t * 8]);
      gld16(Bb + (long)row * ldb + (kt + sc), &Bsm[j * 2048 + t * 8]);
    }
    __syncthreads();

#pragma unroll
    for (int h2 = 0; h2 < 2; h2++) {
      bf16x8 af[4], bfr[4];
#pragma unroll
      for (int i = 0; i < 4; i++) {
        int ra = wm + i * 16 + r16;
        af[i]  = *(const bf16x8*)&Asm[ra * 64 + ((((h2 << 2) + q) ^ (ra & 7)) << 3)];
        int rb = wn + i * 16 + r16;
        bfr[i] = *(const bf16x8*)&Bsm[rb * 64 + ((((h2 << 2) + q) ^ (rb & 7)) << 3)];
      }
#pragma unroll
      for (int mi = 0; mi < 4; mi++)
#pragma unroll
        for (int ni = 0; ni < 4; ni++)
          acc[mi][ni] = __builtin_amdgcn_mfma_f32_16x16x32_bf16(af[mi], bfr[ni], acc[mi][ni], 0, 0, 0);
    }
    __syncthreads();
  }

  if (mode >= 2) {
    float* C = (float*)Cv;
#pragma unroll
    for (int mi = 0; mi < 4; mi++)
#pragma unroll
      for (int ni = 0; ni < 4; ni++)
#pragma unroll
        for (int r = 0; r < 4; r++) {
          int gm = m0 + wm + mi * 16 + q * 4 + r;
          int gn = n0 + wn + ni * 16 + r16;
          long idx = coff + (long)gm * ldc + gn;
          float v = acc[mi][ni][r];
          if (mode == 3) v += C[idx];
          C[idx] = v;
        }
  } else {
    bf16* C = (bf16*)Cv;
#pragma unroll
    for (int mi = 0; mi < 4; mi++)
#pragma unroll
      for (int ni = 0; ni < 4; ni++)
#pragma unroll
        for (int r = 0; r < 4; r++) {
          int gm = m0 + wm + mi * 16 + q * 4 + r;
          int gn = n0 + wn + ni * 16 + r16;
          float v = acc[mi][ni][r];
          if (mode == 1) v *= (float)mask[(long)gm * mask_ld + gn];
          C[coff + (long)gm * ldc + gn] = (bf16)v;
        }
  }
}

// ---------------- final reduce + bias epilogue (fp32 out, float4) ------------
__global__ void k_out(const float* __restrict__ Cp, const float* __restrict__ c0,
                      const float* __restrict__ c1, const float* __restrict__ invln,
                      float* __restrict__ out, int nsplit) {
  int i4 = blockIdx.x * 256 + threadIdx.x;          // 524288
  long i = (long)i4 * 4;
  int n = (int)(i & 2047), m = (int)(i >> 11);
  float4 v = *(const float4*)(Cp + i);
  for (int z = 1; z < nsplit; z++) {
    float4 u = *(const float4*)(Cp + i + (long)z * 2097152);
    v.x += u.x; v.y += u.y; v.z += u.z; v.w += u.w;
  }
  float il = invln[m];
  float4 a = *(const float4*)(c0 + n);
  float4 b = *(const float4*)(c1 + n);
  v.x += a.x + b.x * il;
  v.y += a.y + b.y * il;
  v.z += a.z + b.z * il;
  v.w += a.w + b.w * il;
  *(float4*)(out + i) = v;
}

// ---------------- host ----------------

extern "C" void kernel_launch(void* const* d_in, const int* in_sizes, int n_in,
                              void* d_out, int out_size, void* d_ws, size_t ws_size,
                              hipStream_t stream) {
  (void)out_size;
  float* out = (float*)d_out;

  // ---- resolve inputs by size (order-agnostic) ----
  int iresid = -1, iln = -1, iprobs = -1, iencb = -1, ipruned = -1, imask = -1;
  int iwo = -1, iwv = -1, iencw = -1, iupdw = -1, ibdec = -1, iupb = -1;
  for (int i = 0; i < n_in; i++) {
    switch (in_sizes[i]) {
      case 786432:  iresid  = i; break;
      case 1024:    iln     = i; break;
      case 3145728: iprobs  = i; break;
      case 2048:    iencb   = i; break;
      case 2097152: ipruned = i; break;
      case 4194304: imask   = i; break;
      case 589824:  if (iwo   < 0) iwo   = i; else iwv   = i; break;
      case 1572864: if (iencw < 0) iencw = i; else iupdw = i; break;
      case 768:     if (ibdec < 0) ibdec = i; else iupb  = i; break;
      default: break;
    }
  }
  bool ok = n_in == 12 && iresid >= 0 && iln >= 0 && iprobs >= 0 && iencb >= 0 &&
            ipruned >= 0 && imask >= 0 && iwo >= 0 && iwv >= 0 && iencw >= 0 &&
            iupdw >= 0 && ibdec >= 0 && iupb >= 0;
  if (!ok) { k_sentinel<<<8192, 256, 0, stream>>>(out); return; }

  const float* resid = (const float*)d_in[iresid];
  const float* lns   = (const float*)d_in[iln];
  const float* probs = (const float*)d_in[iprobs];
  const float* W_O   = (const float*)d_in[iwo];
  const float* W_V   = (const float*)d_in[iwv];
  const float* enc_W = (const float*)d_in[iencw];
  const float* enc_b = (const float*)d_in[iencb];
  const float* b_dec = (const float*)d_in[ibdec];
  const float* updW  = (const float*)d_in[iupdw];
  const float* up_b  = (const float*)d_in[iupb];
  const float* pruned= (const float*)d_in[ipruned];
  const int*   cmask = (const int*)d_in[imask];

  // ---- workspace config ----
  const size_t fixedB =
      2359296ull   // WOb
    + 2359296ull   // WVb
    + 2359296ull   // WVt
    + 6291456ull   // G_t
    + 3145728ull   // updWt
    + 1572864ull   // Xt
    + 4194304ull   // Ut
    + 6291456ull   // E1
    + 3145728ull   // encWb
    + 6291456ull   // probsb
    + 8388608ull   // maskb
    + 65536ull;
  auto abBytes = [](int g) -> size_t {
    return (size_t)1024 * g * 2816 * 2 + (size_t)2048 * g * 2816 * 2;
  };
  const size_t margin = 4ull << 20;
  // (gs, nsplit) ladder; prefer gs=12 (one fused final GEMM) + nsplit=8
  // (1024 blocks = 4 blocks/CU on the final GEMM).
  const int cgs[12] = {12, 12, 12, 6, 6, 4, 3, 2, 2, 1, 1, 1};
  const int cns[12] = { 8,  6,  4, 4, 2, 4, 4, 4, 2, 4, 2, 1};
  int gs = 0, nsplit = 0;
  for (int ci = 0; ci < 12; ci++) {
    if (fixedB + (size_t)cns[ci] * 1024 * 2048 * 4 + abBytes(cgs[ci]) + margin <= ws_size) {
      gs = cgs[ci]; nsplit = cns[ci]; break;
    }
  }
  if (gs == 0) { gs = 1; nsplit = 1; }

  char* p = (char*)d_ws;
  auto alloc = [&](size_t bytes) -> char* {
    char* r = p; p += (bytes + 255) & ~(size_t)255; return r;
  };
  bf16*  WOb    = (bf16*)alloc(12ull * 128 * 768 * 2);
  bf16*  WVb    = (bf16*)alloc(12ull * 768 * 128 * 2);
  bf16*  WVt    = (bf16*)alloc(12ull * 128 * 768 * 2);
  bf16*  G_t    = (bf16*)alloc(12ull * 2048 * 128 * 2);
  bf16*  updWt  = (bf16*)alloc(2048ull * 768 * 2);
  bf16*  Xt     = (bf16*)alloc(4ull * 768 * 256 * 2);
  bf16*  Ut     = (bf16*)alloc(4ull * 2048 * 256 * 2);
  bf16*  E1     = (bf16*)alloc(12ull * 2048 * 128 * 2);
  bf16*  encWb  = (bf16*)alloc(2048ull * 768 * 2);
  bf16*  probsb = (bf16*)alloc(4ull * 12 * 256 * 256 * 2);
  bf16*  maskb  = (bf16*)alloc(2048ull * 2048 * 2);
  float* invln  = (float*)alloc(1024 * 4);
  float* t_hk   = (float*)alloc(768 * 4);
  float* wv     = (float*)alloc(768 * 4);
  float* c0     = (float*)alloc(2048 * 4);
  float* c1     = (float*)alloc(2048 * 4);
  float* Cpart  = (float*)alloc((size_t)nsplit * 1024 * 2048 * 4);
  bf16*  A_g    = (bf16*)alloc((size_t)1024 * gs * 2816 * 2);
  bf16*  B_g    = (bf16*)alloc((size_t)2048 * gs * 2816 * 2);

  const long Kg = (long)gs * 2816;

  // ---- prep ----
  k_invln<<<4, 256, 0, stream>>>(lns, invln);
  k_cast4<<<1536, 256, 0, stream>>>(enc_W, encWb, 393216);
  k_cast4<<<3072, 256, 0, stream>>>(probs, probsb, 786432);
  k_maskb<<<4096, 256, 0, stream>>>(cmask, maskb, 1048576);
  k_WO<<<4608, 256, 0, stream>>>(W_O, WOb);
  k_WV<<<4608, 256, 0, stream>>>(W_V, WVb);
  k_WVtT<<<dim3(4, 24, 12), 256, 0, stream>>>(W_V, WVt);
  k_updWtT<<<dim3(64, 24), 256, 0, stream>>>(updW, updWt);
  k_XtT<<<dim3(24, 8, 4), 256, 0, stream>>>(resid, invln, Xt);
  k_UtT<<<dim3(64, 8, 4), 256, 0, stream>>>(pruned, invln, Ut);
  k_bias_t<<<768, 256, 0, stream>>>(W_V, up_b, t_hk);
  k_bias_w<<<768, 256, 0, stream>>>(W_O, t_hk, wv);
  k_bias_c<<<2048, 256, 0, stream>>>(enc_W, enc_b, b_dec, wv, c0, c1);

  // Merged E1 + G_t (z = 24, bb = z/12 selects the problem via pointer-diff
  // batch strides, hh = z%12 the head):
  //   bb=0: E1[h][f][k]  = encWb[f,o] . WOb[h][k][o]
  //   bb=1: G_t[h][u][k] = updWt[u,i] . WVt[h][k][i]
  // Both are M=2048 N=128 K=768, lda=ldb=768, ldc=128.
  gemm_bt<<<dim3(1, 16, 24), 256, 0, stream>>>(
      encWb, WOb, E1, 2048, 128, 768,
      768, 768, 128, 12,
      (long)(updWt - encWb), 0,
      (long)(WVt - WOb), (long)128 * 768,
      (long)(G_t - E1), (long)2048 * 128,
      0, 0, nullptr, 0);

  // ---- head-group loop (single iteration when gs==12) ----
  for (int g = 0; g < 12 / gs; g++) {
    // M_g: B_g[f][hh*768 + i] = E1_h[f,k] . WVb_h[i,k]   M=2048 N=768 K=128
    gemm_bt<<<dim3(6, 16, gs), 256, 0, stream>>>(
        E1 + (long)g * gs * 2048 * 128, WVb + (long)g * gs * 768 * 128, B_g,
        2048, 768, 128,
        128, 128, Kg, gs,
        0, (long)2048 * 128, 0, (long)768 * 128, 0, 768,
        0, 0, nullptr, 0);

    // V_g: B_g[f][gs*768 + hh*2048 + u] = maskb[f,u] * (E1_h[f,k] . G_t_h[u,k])  K=128
    gemm_bt<<<dim3(16, 16, gs), 256, 0, stream>>>(
        E1 + (long)g * gs * 2048 * 128, G_t + (long)g * gs * 2048 * 128, B_g + (long)gs * 768,
        2048, 2048, 128,
        128, 128, Kg, gs,
        0, (long)2048 * 128, 0, (long)2048 * 128, 0, 2048,
        1, 0, maskb, 2048);

    // PX_g: A_g[bq][hh*768 + i] = probsb[b,g*gs+hh][q,s] . Xt[b][i,s]  K=256
    gemm_bt<<<dim3(6, 2, 4 * gs), 256, 0, stream>>>(
        probsb + (long)g * gs * 65536, Xt, A_g,
        256, 768, 256,
        256, 256, Kg, gs,
        (long)12 * 65536, 65536, (long)768 * 256, 0, 256 * Kg, 768,
        0, 0, nullptr, 0);

    // PU_g: A_g[bq][gs*768 + hh*2048 + u] = probsb . Ut[b][u,s]  K=256
    gemm_bt<<<dim3(16, 2, 4 * gs), 256, 0, stream>>>(
        probsb + (long)g * gs * 65536, Ut, A_g + (long)gs * 768,
        256, 2048, 256,
        256, 256, Kg, gs,
        (long)12 * 65536, 65536, (long)2048 * 256, 0, 256 * Kg, 2048,
        0, 0, nullptr, 0);

    // Cpart (+)= A_g[bq,k] . B_g[f,k]   M=1024 N=2048 K=Kg, split-K nsplit
    gemm_bt<<<dim3(16, 8, nsplit), 256, 0, stream>>>(
        A_g, B_g, Cpart,
        1024, 2048, (int)Kg,
        Kg, Kg, 2048, 1,
        0, 0, 0, 0, 0, 0,
        (g == 0) ? 2 : 3, (int)(Kg / nsplit), nullptr, 0);
  }

  // out[b,q,f] = fp32( sum_z Cpart + c0[f] + c1[f]*invln[bq] )
  k_out<<<2048, 256, 0, stream>>>(Cpart, c0, c1, invln, out, nsplit);
}

// Round 2
// 535.202 us; speedup vs baseline: 1.1201x; 1.0495x over previous
//
#include <hip/hip_runtime.h>
#include <hip/hip_bf16.h>
#include <stdint.h>

typedef __bf16 bf16;
typedef __bf16 bf16x8 __attribute__((ext_vector_type(8)));
typedef __bf16 bf16x4 __attribute__((ext_vector_type(4)));
typedef float f32x4 __attribute__((ext_vector_type(4)));

#define AS1 __attribute__((address_space(1)))
#define AS3 __attribute__((address_space(3)))

// B=4, S=256, H=12, DH=64(pad 128), D=768, FD=2048, FU=2048
// R21 (this round):
//  (a) init path restructured: approx_init = (sum_h P_h (X W_V_h W_O_h)) @ enc_W^T
//      -> removes 9216 of final-GEMM K (33792->25344) and the M_g/PX builders;
//      adds tiny T1/T/S GEMMs; S and enc_W are APPENDED as 768 K-columns of the
//      split-K final GEMM (so the S@encW^T contraction rides along for free).
//  (b) workspace overlay: all prep buffers dead before the final GEMM are
//      aliased with Cpart -> nsplit=8 is free up to 64MiB -> gs=12 + nsplit=8
//      fits ~247MiB: ONE final dispatch, grid (16,8,8)=1024 blocks = 4/CU
//      (was 2/CU, Occupancy 20.6%, MfmaUtil 25.6% -> latency-bound).

__device__ __forceinline__ void gld16(const bf16* g, bf16* l) {
  __builtin_amdgcn_global_load_lds((AS1 void*)g, (AS3 void*)l, 16, 0, 0);
}

__global__ void k_sentinel(float* __restrict__ out) {
  int i = blockIdx.x * 256 + threadIdx.x;
  if (i < 2097152) out[i] = 1048576.0f;
}

// ---------------- prep kernels ----------------

__global__ void k_invln(const float* __restrict__ ln, float* __restrict__ invln) {
  int i = blockIdx.x * 256 + threadIdx.x;
  if (i < 1024) invln[i] = 1.0f / ln[i];
}

// vectorized fp32 -> bf16 cast, n4 = n/4
__global__ void k_cast4(const float* __restrict__ s, bf16* __restrict__ d, int n4) {
  int i = blockIdx.x * 256 + threadIdx.x;
  if (i < n4) {
    float4 v = *(const float4*)(s + (long)i * 4);
    bf16x4 o;
    o[0] = (bf16)v.x; o[1] = (bf16)v.y; o[2] = (bf16)v.z; o[3] = (bf16)v.w;
    *(bf16x4*)(d + (long)i * 4) = o;
  }
}

// int32 0/1 mask -> bf16, n4 = n/4
__global__ void k_maskb(const int* __restrict__ m, bf16* __restrict__ d, int n4) {
  int i = blockIdx.x * 256 + threadIdx.x;
  if (i < n4) {
    int4 v = *(const int4*)(m + (long)i * 4);
    bf16x4 o;
    o[0] = (bf16)(float)v.x; o[1] = (bf16)(float)v.y;
    o[2] = (bf16)(float)v.z; o[3] = (bf16)(float)v.w;
    *(bf16x4*)(d + (long)i * 4) = o;
  }
}

// probsT[b][q][h*256+s] = bf16(probs[b,h,q,s])   (contiguous in s both sides)
__global__ void k_probsT(const float* __restrict__ probs, bf16* __restrict__ pT) {
  int i = blockIdx.x * 256 + threadIdx.x;   // 786432 vec4s
  if (i < 786432) {
    long idx = (long)i * 4;
    int s  = (int)(idx & 255);
    int q  = (int)((idx >> 8) & 255);
    int hb = (int)(idx >> 16);
    int h = hb % 12, b = hb / 12;
    float4 v = *(const float4*)(probs + idx);
    bf16x4 o;
    o[0] = (bf16)v.x; o[1] = (bf16)v.y; o[2] = (bf16)v.z; o[3] = (bf16)v.w;
    *(bf16x4*)(pT + (long)b * 786432 + (long)q * 3072 + h * 256 + s) = o;
  }
}

__global__ void k_WO(const float* __restrict__ W_O, bf16* __restrict__ WOb) {
  int i = blockIdx.x * 256 + threadIdx.x;           // 12*128*768
  int o = i % 768, r = (i / 768) & 127, h = i / (768 * 128);
  WOb[i] = (r < 64) ? (bf16)W_O[(long)(h * 64 + r) * 768 + o] : (bf16)0.0f;
}

// WVt[h][k<128][i<768] = W_V[h,i,k]  (tiled transpose, zero-pad k>=64)
__global__ void k_WVtT(const float* __restrict__ wv, bf16* __restrict__ WVt) {
  __shared__ float tile[32][33];
  int h = blockIdx.z;                 // 12
  int k0 = blockIdx.x * 32;           // 0..96
  int i0 = blockIdx.y * 32;           // 24 tiles
  int lane = threadIdx.x & 31, rg = threadIdx.x >> 5;
  if (k0 < 64) {
    for (int r = rg; r < 32; r += 8)
      tile[r][lane] = wv[((long)(h * 768 + i0 + r)) * 64 + k0 + lane];
    __syncthreads();
    for (int r = rg; r < 32; r += 8)
      WVt[((long)h * 128 + k0 + r) * 768 + i0 + lane] = (bf16)tile[lane][r];
  } else {
    for (int r = rg; r < 32; r += 8)
      WVt[((long)h * 128 + k0 + r) * 768 + i0 + lane] = (bf16)0.0f;
  }
}

// W_Ot[h][o][k64] = W_O[h,k,o]  (tiled transpose)
__global__ void k_WOt(const float* __restrict__ wo, bf16* __restrict__ W_Ot) {
  __shared__ float tile[32][33];
  int h = blockIdx.z;                 // 12
  int k0 = blockIdx.x * 32;           // 0..32
  int o0 = blockIdx.y * 32;           // 24 tiles
  int lane = threadIdx.x & 31, rg = threadIdx.x >> 5;
  for (int r = rg; r < 32; r += 8)
    tile[r][lane] = wo[((long)(h * 64 + k0 + r)) * 768 + o0 + lane];
  __syncthreads();
  for (int r = rg; r < 32; r += 8)
    W_Ot[((long)(h * 768 + o0 + r)) * 64 + k0 + lane] = (bf16)tile[lane][r];
}

// updWt[u][i] = up_dec_W[i][u]  (tiled transpose)
__global__ void k_updWtT(const float* __restrict__ u, bf16* __restrict__ d) {
  __shared__ float tile[32][33];
  int u0 = blockIdx.x * 32;           // 64 tiles
  int i0 = blockIdx.y * 32;           // 24 tiles
  int lane = threadIdx.x & 31, rg = threadIdx.x >> 5;
  for (int r = rg; r < 32; r += 8)
    tile[r][lane] = u[((long)(i0 + r)) * 2048 + u0 + lane];
  __syncthreads();
  for (int r = rg; r < 32; r += 8)
    d[((long)(u0 + r)) * 768 + i0 + lane] = (bf16)tile[lane][r];
}

// Xb[b*256+s][d] = resid[b,s,d] * invln (row-major bf16, no transpose)
__global__ void k_Xb(const float* __restrict__ resid, const float* __restrict__ invln,
                     bf16* __restrict__ Xb) {
  int i = blockIdx.x * 256 + threadIdx.x;   // 196608 vec4s
  if (i < 196608) {
    long idx = (long)i * 4;
    float il = invln[idx / 768];            // 4|768 so chunk never straddles rows
    float4 v = *(const float4*)(resid + idx);
    bf16x4 o;
    o[0] = (bf16)(v.x * il); o[1] = (bf16)(v.y * il);
    o[2] = (bf16)(v.z * il); o[3] = (bf16)(v.w * il);
    *(bf16x4*)(Xb + idx) = o;
  }
}

// Ut[b][u][s] = pruned[b,s,u] * invln  (tiled transpose)
__global__ void k_UtT(const float* __restrict__ pr, const float* __restrict__ invln,
                      bf16* __restrict__ Ut) {
  __shared__ float tile[32][33];
  int b = blockIdx.z, u0 = blockIdx.x * 32, s0 = blockIdx.y * 32;  // (64, 8, 4)
  int lane = threadIdx.x & 31, rg = threadIdx.x >> 5;
  for (int r = rg; r < 32; r += 8) {
    int s = s0 + r;
    tile[r][lane] = pr[((long)(b * 256 + s)) * 2048 + u0 + lane] * invln[b * 256 + s];
  }
  __syncthreads();
  for (int r = rg; r < 32; r += 8)
    Ut[((long)b * 2048 + u0 + r) * 256 + s0 + lane] = (bf16)tile[lane][r];
}

// append enc_W (bf16) as the 768-column K-tail of B_g
__global__ void k_append(const bf16* __restrict__ encWb, bf16* __restrict__ Bt, long ldb) {
  int i = blockIdx.x * 256 + threadIdx.x;   // 196608 vec8s
  if (i < 196608) {
    long idx = (long)i * 8;
    int f = (int)(idx / 768), d = (int)(idx % 768);
    *(bf16x8*)(Bt + (long)f * ldb + d) = *(const bf16x8*)(encWb + idx);
  }
}

// ---------------- bias chain (fp32, block-parallel) ----------------

__device__ __forceinline__ float blk_reduce(float s) {
  __shared__ float red[256];
  red[threadIdx.x] = s; __syncthreads();
  for (int o = 128; o > 0; o >>= 1) {
    if ((int)threadIdx.x < o) red[threadIdx.x] += red[threadIdx.x + o];
    __syncthreads();
  }
  float r = red[0]; __syncthreads();
  return r;
}

__global__ void k_bias_t(const float* __restrict__ W_V, const float* __restrict__ up_b,
                         float* __restrict__ t_hk) {
  int j = blockIdx.x, h = j >> 6, k = j & 63;
  float s = 0.f;
  for (int m = threadIdx.x; m < 768; m += 256)
    s += W_V[((long)(h * 768 + m)) * 64 + k] * up_b[m];
  float r = blk_reduce(s);
  if (threadIdx.x == 0) t_hk[j] = r;
}

__global__ void k_bias_w(const float* __restrict__ W_O, const float* __restrict__ t_hk,
                         float* __restrict__ w) {
  int d = blockIdx.x;
  float s = 0.f;
  for (int j = threadIdx.x; j < 768; j += 256)
    s += W_O[(long)j * 768 + d] * t_hk[j];
  float r = blk_reduce(s);
  if (threadIdx.x == 0) w[d] = r;
}

__global__ void k_bias_c(const float* __restrict__ enc_W, const float* __restrict__ enc_b,
                         const float* __restrict__ b_dec, const float* __restrict__ w,
                         float* __restrict__ c0, float* __restrict__ c1) {
  int f = blockIdx.x;
  float s0 = 0.f, s1 = 0.f;
  for (int d = threadIdx.x; d < 768; d += 256) {
    float e = enc_W[(long)f * 768 + d];
    s0 += e * b_dec[d];
    s1 += e * w[d];
  }
  float r0 = blk_reduce(s0);
  float r1 = blk_reduce(s1);
  if (threadIdx.x == 0) { c0[f] = enc_b[f] - r0; c1[f] = r1; }
}

// ---------------- GEMM (BT form: C[m,n] = sum_k A[m,k]*B[n,k]) ----------------
// BK=64, XOR-swizzled staging. K (and kChunk) must be multiples of 64.
// mode 0: bf16 store; mode 1: *= bf16 mask, bf16 store;
// mode 2: split-K fp32 overwrite; mode 3: split-K fp32 read-accumulate
__global__ __launch_bounds__(256)
void gemm_bt(const bf16* __restrict__ A, const bf16* __restrict__ B, void* __restrict__ Cv,
             int M, int N, int K,
             long lda, long ldb, long ldc,
             int batchH,
             long sa_b, long sa_h, long sb_b, long sb_h, long sc_b, long sc_h,
             int mode, int kChunk,
             const bf16* __restrict__ mask, long mask_ld)
{
  __shared__ __align__(16) bf16 Asm[128 * 64];
  __shared__ __align__(16) bf16 Bsm[128 * 64];

  const int t = threadIdx.x;

  // T1: bijective XCD-aware remap of the (x,y) tile id (m204 formula),
  // M-fastest so same-XCD blocks share B panels.
  const int nbx = gridDim.x, nby = gridDim.y;
  const int nxy = nbx * nby;
  int orig = blockIdx.x + nbx * blockIdx.y;
  int qq = nxy >> 3, rr = nxy & 7;
  int xcd = orig & 7, lid = orig >> 3;
  int swz = (xcd < rr) ? (xcd * (qq + 1) + lid)
                       : (rr * (qq + 1) + (xcd - rr) * qq + lid);
  const int m0 = (swz % nby) * 128;
  const int n0 = (swz / nby) * 128;

  long aoff, boff, coff;
  int k0, k1;
  if (mode >= 2) {
    int z = blockIdx.z;
    aoff = 0; boff = 0;
    coff = (long)z * (long)M * ldc;
    k0 = z * kChunk; k1 = k0 + kChunk; if (k1 > K) k1 = K;
  } else {
    int z = blockIdx.z;
    int bb = z / batchH, hh = z - bb * batchH;
    aoff = (long)bb * sa_b + (long)hh * sa_h;
    boff = (long)bb * sb_b + (long)hh * sb_h;
    coff = (long)bb * sc_b + (long)hh * sc_h;
    k0 = 0; k1 = K;
  }

  const bf16* Ab = A + aoff + (long)m0 * lda;
  const bf16* Bb = B + boff + (long)n0 * ldb;

  const int r0 = t >> 3;           // 0..31 (staging row within 32-row group)
  const int g8 = t & 7;            // staging col-group (LDS slot)

  const int L = t & 63, w = t >> 6;
  const int wm = (w & 1) * 64, wn = (w >> 1) * 64;
  const int r16 = L & 15, q = L >> 4;

  f32x4 acc[4][4];
#pragma unroll
  for (int i = 0; i < 4; i++)
#pragma unroll
    for (int j = 0; j < 4; j++) acc[i][j] = (f32x4){0.f, 0.f, 0.f, 0.f};

  for (int kt = k0; kt < k1; kt += 64) {
#pragma unroll
    for (int j = 0; j < 4; j++) {
      int row = j * 32 + r0;
      int sc = ((g8 ^ (row & 7)) << 3);      // source col swizzle
      gld16(Ab + (long)row * lda + (kt + sc), &Asm[j * 2048 + t * 8]);
      gld16(Bb + (long)row * ldb + (kt + sc), &Bsm[j * 2048 + t * 8]);
    }
    __syncthreads();

#pragma unroll
    for (int h2 = 0; h2 < 2; h2++) {
      bf16x8 af[4], bfr[4];
#pragma unroll
      for (int i = 0; i < 4; i++) {
        int ra = wm + i * 16 + r16;
        af[i]  = *(const bf16x8*)&Asm[ra * 64 + ((((h2 << 2) + q) ^ (ra & 7)) << 3)];
        int rb = wn + i * 16 + r16;
        bfr[i] = *(const bf16x8*)&Bsm[rb * 64 + ((((h2 << 2) + q) ^ (rb & 7)) << 3)];
      }
#pragma unroll
      for (int mi = 0; mi < 4; mi++)
#pragma unroll
        for (int ni = 0; ni < 4; ni++)
          acc[mi][ni] = __builtin_amdgcn_mfma_f32_16x16x32_bf16(af[mi], bfr[ni], acc[mi][ni], 0, 0, 0);
    }
    __syncthreads();
  }

  if (mode >= 2) {
    float* C = (float*)Cv;
#pragma unroll
    for (int mi = 0; mi < 4; mi++)
#pragma unroll
      for (int ni = 0; ni < 4; ni++)
#pragma unroll
        for (int r = 0; r < 4; r++) {
          int gm = m0 + wm + mi * 16 + q * 4 + r;
          int gn = n0 + wn + ni * 16 + r16;
          long idx = coff + (long)gm * ldc + gn;
          float v = acc[mi][ni][r];
          if (mode == 3) v += C[idx];
          C[idx] = v;
        }
  } else {
    bf16* C = (bf16*)Cv;
#pragma unroll
    for (int mi = 0; mi < 4; mi++)
#pragma unroll
      for (int ni = 0; ni < 4; ni++)
#pragma unroll
        for (int r = 0; r < 4; r++) {
          int gm = m0 + wm + mi * 16 + q * 4 + r;
          int gn = n0 + wn + ni * 16 + r16;
          float v = acc[mi][ni][r];
          if (mode == 1) v *= (float)mask[(long)gm * mask_ld + gn];
          C[coff + (long)gm * ldc + gn] = (bf16)v;
        }
  }
}

// ---------------- final reduce + bias epilogue (fp32 out, float4) ------------
__global__ void k_out(const float* __restrict__ Cp, const float* __restrict__ c0,
                      const float* __restrict__ c1, const float* __restrict__ invln,
                      float* __restrict__ out, int nsplit) {
  int i4 = blockIdx.x * 256 + threadIdx.x;          // 524288
  long i = (long)i4 * 4;
  int n = (int)(i & 2047), m = (int)(i >> 11);
  float4 v = *(const float4*)(Cp + i);
  for (int z = 1; z < nsplit; z++) {
    float4 u = *(const float4*)(Cp + i + (long)z * 2097152);
    v.x += u.x; v.y += u.y; v.z += u.z; v.w += u.w;
  }
  float il = invln[m];
  float4 a = *(const float4*)(c0 + n);
  float4 b = *(const float4*)(c1 + n);
  v.x += a.x + b.x * il;
  v.y += a.y + b.y * il;
  v.z += a.z + b.z * il;
  v.w += a.w + b.w * il;
  *(float4*)(out + i) = v;
}

// ---------------- host ----------------

extern "C" void kernel_launch(void* const* d_in, const int* in_sizes, int n_in,
                              void* d_out, int out_size, void* d_ws, size_t ws_size,
                              hipStream_t stream) {
  (void)out_size;
  float* out = (float*)d_out;

  // ---- resolve inputs by size (order-agnostic) ----
  int iresid = -1, iln = -1, iprobs = -1, iencb = -1, ipruned = -1, imask = -1;
  int iwo = -1, iwv = -1, iencw = -1, iupdw = -1, ibdec = -1, iupb = -1;
  for (int i = 0; i < n_in; i++) {
    switch (in_sizes[i]) {
      case 786432:  iresid  = i; break;
      case 1024:    iln     = i; break;
      case 3145728: iprobs  = i; break;
      case 2048:    iencb   = i; break;
      case 2097152: ipruned = i; break;
      case 4194304: imask   = i; break;
      case 589824:  if (iwo   < 0) iwo   = i; else iwv   = i; break;
      case 1572864: if (iencw < 0) iencw = i; else iupdw = i; break;
      case 768:     if (ibdec < 0) ibdec = i; else iupb  = i; break;
      default: break;
    }
  }
  bool ok = n_in == 12 && iresid >= 0 && iln >= 0 && iprobs >= 0 && iencb >= 0 &&
            ipruned >= 0 && imask >= 0 && iwo >= 0 && iwv >= 0 && iencw >= 0 &&
            iupdw >= 0 && ibdec >= 0 && iupb >= 0;
  if (!ok) { k_sentinel<<<8192, 256, 0, stream>>>(out); return; }

  const float* resid = (const float*)d_in[iresid];
  const float* lns   = (const float*)d_in[iln];
  const float* probs = (const float*)d_in[iprobs];
  const float* W_O   = (const float*)d_in[iwo];
  const float* W_V   = (const float*)d_in[iwv];
  const float* enc_W = (const float*)d_in[iencw];
  const float* enc_b = (const float*)d_in[iencb];
  const float* b_dec = (const float*)d_in[ibdec];
  const float* updW  = (const float*)d_in[iupdw];
  const float* up_b  = (const float*)d_in[iupb];
  const float* pruned= (const float*)d_in[ipruned];
  const int*   cmask = (const int*)d_in[imask];

  // ---- workspace sizing ----
  auto pad = [](size_t b) -> size_t { return (b + 255) & ~(size_t)255; };
  // overlay prep buffers (ALL dead before the first final-GEMM dispatch):
  const size_t prepB = pad(2359296) + pad(2359296) + pad(3145728) + pad(1572864) +
                       pad(3145728) + pad(1179648) + pad(3145728) + pad(18874368);
  // persistent (live across the g-loop): G_t, Ut, E1, probsT, maskb + smalls
  const size_t persB = pad(6291456) + pad(4194304) + pad(6291456) + pad(6291456) +
                       pad(8388608) + pad(4096) + pad(3072) + pad(3072) +
                       pad(8192) + pad(8192);
  auto needB = [&](int g, int ns) -> size_t {
    size_t cp = (size_t)ns * 8388608;
    size_t ov = prepB > cp ? prepB : cp;
    long KA = (long)g * 2048 + 768;
    size_t ab = pad((size_t)1024 * KA * 2) + pad((size_t)2048 * KA * 2);
    return ov + persB + ab + (2ull << 20);   // 2MiB slack
  };
  const int cgs[14] = {12, 12, 6, 6, 4, 4, 3, 3, 2, 2, 1, 1, 1, 1};
  const int cns[14] = { 8,  4, 8, 4, 8, 4, 8, 4, 8, 4, 8, 4, 2, 1};
  int gs = 0, nsplit = 0;
  for (int ci = 0; ci < 14; ci++) {
    if (needB(cgs[ci], cns[ci]) <= ws_size) { gs = cgs[ci]; nsplit = cns[ci]; break; }
  }
  if (gs == 0) { gs = 1; nsplit = 1; }

  const long KA = (long)gs * 2048 + 768;     // A_g/B_g leading dim (K incl. tail)

  char* p = (char*)d_ws;
  auto alloc = [&](size_t bytes) -> char* {
    char* r = p; p += (bytes + 255) & ~(size_t)255; return r;
  };
  // -- overlay region: prep buffers, later reused as Cpart --
  char* overlayBase = p;
  bf16*  WOb    = (bf16*)alloc(12ull * 128 * 768 * 2);
  bf16*  WVt    = (bf16*)alloc(12ull * 128 * 768 * 2);
  bf16*  updWt  = (bf16*)alloc(2048ull * 768 * 2);
  bf16*  Xb     = (bf16*)alloc(1024ull * 768 * 2);
  bf16*  encWb  = (bf16*)alloc(2048ull * 768 * 2);
  bf16*  W_Ot   = (bf16*)alloc(12ull * 768 * 64 * 2);
  bf16*  T1     = (bf16*)alloc(12ull * 1024 * 128 * 2);
  bf16*  T3     = (bf16*)alloc(4ull * 768 * 3072 * 2);
  {
    size_t used = (size_t)(p - overlayBase);
    size_t cp = (size_t)nsplit * 8388608;
    p = overlayBase + (used > cp ? used : cp);
  }
  float* Cpart  = (float*)overlayBase;       // aliases dead prep buffers
  // -- persistent region --
  bf16*  G_t    = (bf16*)alloc(12ull * 2048 * 128 * 2);
  bf16*  Ut     = (bf16*)alloc(4ull * 2048 * 256 * 2);
  bf16*  E1     = (bf16*)alloc(12ull * 2048 * 128 * 2);
  bf16*  probsT = (bf16*)alloc(4ull * 256 * 3072 * 2);
  bf16*  maskb  = (bf16*)alloc(2048ull * 2048 * 2);
  float* invln  = (float*)alloc(1024 * 4);
  float* t_hk   = (float*)alloc(768 * 4);
  float* wv     = (float*)alloc(768 * 4);
  float* c0     = (float*)alloc(2048 * 4);
  float* c1     = (float*)alloc(2048 * 4);
  bf16*  A_g    = (bf16*)alloc((size_t)1024 * KA * 2);
  bf16*  B_g    = (bf16*)alloc((size_t)2048 * KA * 2);

  // ---- prep ----
  k_invln<<<4, 256, 0, stream>>>(lns, invln);
  k_cast4<<<1536, 256, 0, stream>>>(enc_W, encWb, 393216);
  k_probsT<<<3072, 256, 0, stream>>>(probs, probsT);
  k_maskb<<<4096, 256, 0, stream>>>(cmask, maskb, 1048576);
  k_WO<<<4608, 256, 0, stream>>>(W_O, WOb);
  k_WVtT<<<dim3(4, 24, 12), 256, 0, stream>>>(W_V, WVt);
  k_WOt<<<dim3(2, 24, 12), 256, 0, stream>>>(W_O, W_Ot);
  k_updWtT<<<dim3(64, 24), 256, 0, stream>>>(updW, updWt);
  k_Xb<<<768, 256, 0, stream>>>(resid, invln, Xb);
  k_UtT<<<dim3(64, 8, 4), 256, 0, stream>>>(pruned, invln, Ut);
  k_bias_t<<<768, 256, 0, stream>>>(W_V, up_b, t_hk);
  k_bias_w<<<768, 256, 0, stream>>>(W_O, t_hk, wv);
  k_bias_c<<<2048, 256, 0, stream>>>(enc_W, enc_b, b_dec, wv, c0, c1);

  // Merged E1 + G_t (z = 24, bb selects the problem via pointer-diff strides):
  //   bb=0: E1[h][f][k]  = encWb[f,o] . WOb[h][k][o]
  //   bb=1: G_t[h][u][k] = updWt[u,i] . WVt[h][k][i]
  gemm_bt<<<dim3(1, 16, 24), 256, 0, stream>>>(
      encWb, WOb, E1, 2048, 128, 768,
      768, 768, 128, 12,
      (long)(updWt - encWb), 0,
      (long)(WVt - WOb), (long)128 * 768,
      (long)(G_t - E1), (long)2048 * 128,
      0, 0, nullptr, 0);

  // ---- init path: T1 -> T3 -> S (appended into A_g K-tail) ----
  // T1[h][bs][k128] = Xb[bs,i] . WVt[h][k][i]   M=1024 N=128 K=768 (z=h)
  gemm_bt<<<dim3(1, 8, 12), 256, 0, stream>>>(
      Xb, WVt, T1, 1024, 128, 768,
      768, 768, 128, 12,
      0, 0, 0, (long)128 * 768, 0, (long)1024 * 128,
      0, 0, nullptr, 0);

  // T3[b][o][h*256+s] = W_Ot[h][o][k] . T1[h][b*256+s][k]   M=768 N=256 K=64
  // z=(b,h) via batchH=12
  gemm_bt<<<dim3(2, 6, 48), 256, 0, stream>>>(
      W_Ot, T1, T3, 768, 256, 64,
      64, 128, 3072, 12,
      0, (long)768 * 64, (long)256 * 128, (long)1024 * 128, 2359296, 256,
      0, 0, nullptr, 0);

  // S[b][q][o] = probsT[b][q][hs] . T3[b][o][hs]  -> A_g[:, gs*2048 .. +768]
  // M=256 N=768 K=3072 (z=b)
  gemm_bt<<<dim3(6, 2, 4), 256, 0, stream>>>(
      probsT, T3, A_g + (long)gs * 2048, 256, 768, 3072,
      3072, 3072, KA, 1,
      786432, 0, 2359296, 0, 256 * KA, 0,
      0, 0, nullptr, 0);

  // B_g K-tail: enc_W columns (so S @ enc_W^T rides inside the final GEMM)
  k_append<<<768, 256, 0, stream>>>(encWb, B_g + (long)gs * 2048, KA);

  // ---- head-group loop (single iteration when gs==12) ----
  for (int g = 0; g < 12 / gs; g++) {
    // V_g: B_g[f][hh*2048+u] = maskb[f,u] * (E1_h[f,k] . G_t_h[u,k])  K=128
    gemm_bt<<<dim3(16, 16, gs), 256, 0, stream>>>(
        E1 + (long)g * gs * 2048 * 128, G_t + (long)g * gs * 2048 * 128, B_g,
        2048, 2048, 128,
        128, 128, KA, gs,
        0, (long)2048 * 128, 0, (long)2048 * 128, 0, 2048,
        1, 0, maskb, 2048);

    // PU_g: A_g[b*256+q][hh*2048+u] = probsT[b][q][(g*gs+hh)*256 + s] . Ut[b][u][s]
    // M=256 N=2048 K=256, z=(b,hh) via batchH=gs
    gemm_bt<<<dim3(16, 2, 4 * gs), 256, 0, stream>>>(
        probsT + (long)g * gs * 256, Ut, A_g,
        256, 2048, 256,
        3072, 256, KA, gs,
        786432, 256, (long)2048 * 256, 0, 256 * KA, 2048,
        0, 0, nullptr, 0);

    // Cpart (+)= A_g[bq,k] . B_g[f,k]
    // g==0 includes the 768-col [S | enc_W] tail; g>0 only the gs*2048 cols.
    int Kthis = (g == 0) ? (int)KA : gs * 2048;
    int kc = ((Kthis / nsplit + 63) / 64) * 64;
    gemm_bt<<<dim3(16, 8, nsplit), 256, 0, stream>>>(
        A_g, B_g, Cpart,
        1024, 2048, Kthis,
        KA, KA, 2048, 1,
        0, 0, 0, 0, 0, 0,
        (g == 0) ? 2 : 3, kc, nullptr, 0);
  }

  // out[b,q,f] = fp32( sum_z Cpart + c0[f] + c1[f]*invln[bq] )
  k_out<<<2048, 256, 0, stream>>>(Cpart, c0, c1, invln, out, nsplit);
}

// Round 3
// 505.773 us; speedup vs baseline: 1.1853x; 1.0582x over previous
//
#include <hip/hip_runtime.h>
#include <hip/hip_bf16.h>
#include <stdint.h>

typedef __bf16 bf16;
typedef __bf16 bf16x8 __attribute__((ext_vector_type(8)));
typedef __bf16 bf16x4 __attribute__((ext_vector_type(4)));
typedef float f32x4 __attribute__((ext_vector_type(4)));

#define AS1 __attribute__((address_space(1)))
#define AS3 __attribute__((address_space(3)))

// B=4, S=256, H=12, DH=64(pad 128), D=768, FD=2048, FU=2048
// R22 (this round): the final GEMM (151us, MfmaUtil 30%, HBM 27%) is limited
// by the 2-barrier-per-K-step schedule (vmcnt(0) drain ~1200cy/step), not by
// occupancy/BW. New kernel gemm_fp: 512thr / 8 waves, BK=64, 4 LDS buffers
// (128KiB), depth-3 prefetch with counted s_waitcnt vmcnt(8) (never 0 in
// steady state), ONE barrier per K-step. nsplit 8->2 (grid 16x8x2 = 256
// blocks = 1/CU; Cpart traffic 128->32MB).

__device__ __forceinline__ void gld16(const bf16* g, bf16* l) {
  __builtin_amdgcn_global_load_lds((AS1 void*)g, (AS3 void*)l, 16, 0, 0);
}

__global__ void k_sentinel(float* __restrict__ out) {
  int i = blockIdx.x * 256 + threadIdx.x;
  if (i < 2097152) out[i] = 1048576.0f;
}

// ---------------- prep kernels ----------------

__global__ void k_invln(const float* __restrict__ ln, float* __restrict__ invln) {
  int i = blockIdx.x * 256 + threadIdx.x;
  if (i < 1024) invln[i] = 1.0f / ln[i];
}

// vectorized fp32 -> bf16 cast, n4 = n/4
__global__ void k_cast4(const float* __restrict__ s, bf16* __restrict__ d, int n4) {
  int i = blockIdx.x * 256 + threadIdx.x;
  if (i < n4) {
    float4 v = *(const float4*)(s + (long)i * 4);
    bf16x4 o;
    o[0] = (bf16)v.x; o[1] = (bf16)v.y; o[2] = (bf16)v.z; o[3] = (bf16)v.w;
    *(bf16x4*)(d + (long)i * 4) = o;
  }
}

// int32 0/1 mask -> bf16, n4 = n/4
__global__ void k_maskb(const int* __restrict__ m, bf16* __restrict__ d, int n4) {
  int i = blockIdx.x * 256 + threadIdx.x;
  if (i < n4) {
    int4 v = *(const int4*)(m + (long)i * 4);
    bf16x4 o;
    o[0] = (bf16)(float)v.x; o[1] = (bf16)(float)v.y;
    o[2] = (bf16)(float)v.z; o[3] = (bf16)(float)v.w;
    *(bf16x4*)(d + (long)i * 4) = o;
  }
}

// probsT[b][q][h*256+s] = bf16(probs[b,h,q,s])   (contiguous in s both sides)
__global__ void k_probsT(const float* __restrict__ probs, bf16* __restrict__ pT) {
  int i = blockIdx.x * 256 + threadIdx.x;   // 786432 vec4s
  if (i < 786432) {
    long idx = (long)i * 4;
    int s  = (int)(idx & 255);
    int q  = (int)((idx >> 8) & 255);
    int hb = (int)(idx >> 16);
    int h = hb % 12, b = hb / 12;
    float4 v = *(const float4*)(probs + idx);
    bf16x4 o;
    o[0] = (bf16)v.x; o[1] = (bf16)v.y; o[2] = (bf16)v.z; o[3] = (bf16)v.w;
    *(bf16x4*)(pT + (long)b * 786432 + (long)q * 3072 + h * 256 + s) = o;
  }
}

__global__ void k_WO(const float* __restrict__ W_O, bf16* __restrict__ WOb) {
  int i = blockIdx.x * 256 + threadIdx.x;           // 12*128*768
  int o = i % 768, r = (i / 768) & 127, h = i / (768 * 128);
  WOb[i] = (r < 64) ? (bf16)W_O[(long)(h * 64 + r) * 768 + o] : (bf16)0.0f;
}

// WVt[h][k<128][i<768] = W_V[h,i,k]  (tiled transpose, zero-pad k>=64)
__global__ void k_WVtT(const float* __restrict__ wv, bf16* __restrict__ WVt) {
  __shared__ float tile[32][33];
  int h = blockIdx.z;                 // 12
  int k0 = blockIdx.x * 32;           // 0..96
  int i0 = blockIdx.y * 32;           // 24 tiles
  int lane = threadIdx.x & 31, rg = threadIdx.x >> 5;
  if (k0 < 64) {
    for (int r = rg; r < 32; r += 8)
      tile[r][lane] = wv[((long)(h * 768 + i0 + r)) * 64 + k0 + lane];
    __syncthreads();
    for (int r = rg; r < 32; r += 8)
      WVt[((long)h * 128 + k0 + r) * 768 + i0 + lane] = (bf16)tile[lane][r];
  } else {
    for (int r = rg; r < 32; r += 8)
      WVt[((long)h * 128 + k0 + r) * 768 + i0 + lane] = (bf16)0.0f;
  }
}

// W_Ot[h][o][k64] = W_O[h,k,o]  (tiled transpose)
__global__ void k_WOt(const float* __restrict__ wo, bf16* __restrict__ W_Ot) {
  __shared__ float tile[32][33];
  int h = blockIdx.z;                 // 12
  int k0 = blockIdx.x * 32;           // 0..32
  int o0 = blockIdx.y * 32;           // 24 tiles
  int lane = threadIdx.x & 31, rg = threadIdx.x >> 5;
  for (int r = rg; r < 32; r += 8)
    tile[r][lane] = wo[((long)(h * 64 + k0 + r)) * 768 + o0 + lane];
  __syncthreads();
  for (int r = rg; r < 32; r += 8)
    W_Ot[((long)(h * 768 + o0 + r)) * 64 + k0 + lane] = (bf16)tile[lane][r];
}

// updWt[u][i] = up_dec_W[i][u]  (tiled transpose)
__global__ void k_updWtT(const float* __restrict__ u, bf16* __restrict__ d) {
  __shared__ float tile[32][33];
  int u0 = blockIdx.x * 32;           // 64 tiles
  int i0 = blockIdx.y * 32;           // 24 tiles
  int lane = threadIdx.x & 31, rg = threadIdx.x >> 5;
  for (int r = rg; r < 32; r += 8)
    tile[r][lane] = u[((long)(i0 + r)) * 2048 + u0 + lane];
  __syncthreads();
  for (int r = rg; r < 32; r += 8)
    d[((long)(u0 + r)) * 768 + i0 + lane] = (bf16)tile[lane][r];
}

// Xb[b*256+s][d] = resid[b,s,d] * invln (row-major bf16, no transpose)
__global__ void k_Xb(const float* __restrict__ resid, const float* __restrict__ invln,
                     bf16* __restrict__ Xb) {
  int i = blockIdx.x * 256 + threadIdx.x;   // 196608 vec4s
  if (i < 196608) {
    long idx = (long)i * 4;
    float il = invln[idx / 768];            // 4|768 so chunk never straddles rows
    float4 v = *(const float4*)(resid + idx);
    bf16x4 o;
    o[0] = (bf16)(v.x * il); o[1] = (bf16)(v.y * il);
    o[2] = (bf16)(v.z * il); o[3] = (bf16)(v.w * il);
    *(bf16x4*)(Xb + idx) = o;
  }
}

// Ut[b][u][s] = pruned[b,s,u] * invln  (tiled transpose)
__global__ void k_UtT(const float* __restrict__ pr, const float* __restrict__ invln,
                      bf16* __restrict__ Ut) {
  __shared__ float tile[32][33];
  int b = blockIdx.z, u0 = blockIdx.x * 32, s0 = blockIdx.y * 32;  // (64, 8, 4)
  int lane = threadIdx.x & 31, rg = threadIdx.x >> 5;
  for (int r = rg; r < 32; r += 8) {
    int s = s0 + r;
    tile[r][lane] = pr[((long)(b * 256 + s)) * 2048 + u0 + lane] * invln[b * 256 + s];
  }
  __syncthreads();
  for (int r = rg; r < 32; r += 8)
    Ut[((long)b * 2048 + u0 + r) * 256 + s0 + lane] = (bf16)tile[lane][r];
}

// append enc_W (bf16) as the 768-column K-tail of B_g
__global__ void k_append(const bf16* __restrict__ encWb, bf16* __restrict__ Bt, long ldb) {
  int i = blockIdx.x * 256 + threadIdx.x;   // 196608 vec8s
  if (i < 196608) {
    long idx = (long)i * 8;
    int f = (int)(idx / 768), d = (int)(idx % 768);
    *(bf16x8*)(Bt + (long)f * ldb + d) = *(const bf16x8*)(encWb + idx);
  }
}

// ---------------- bias chain (fp32, block-parallel) ----------------

__device__ __forceinline__ float blk_reduce(float s) {
  __shared__ float red[256];
  red[threadIdx.x] = s; __syncthreads();
  for (int o = 128; o > 0; o >>= 1) {
    if ((int)threadIdx.x < o) red[threadIdx.x] += red[threadIdx.x + o];
    __syncthreads();
  }
  float r = red[0]; __syncthreads();
  return r;
}

__global__ void k_bias_t(const float* __restrict__ W_V, const float* __restrict__ up_b,
                         float* __restrict__ t_hk) {
  int j = blockIdx.x, h = j >> 6, k = j & 63;
  float s = 0.f;
  for (int m = threadIdx.x; m < 768; m += 256)
    s += W_V[((long)(h * 768 + m)) * 64 + k] * up_b[m];
  float r = blk_reduce(s);
  if (threadIdx.x == 0) t_hk[j] = r;
}

__global__ void k_bias_w(const float* __restrict__ W_O, const float* __restrict__ t_hk,
                         float* __restrict__ w) {
  int d = blockIdx.x;
  float s = 0.f;
  for (int j = threadIdx.x; j < 768; j += 256)
    s += W_O[(long)j * 768 + d] * t_hk[j];
  float r = blk_reduce(s);
  if (threadIdx.x == 0) w[d] = r;
}

__global__ void k_bias_c(const float* __restrict__ enc_W, const float* __restrict__ enc_b,
                         const float* __restrict__ b_dec, const float* __restrict__ w,
                         float* __restrict__ c0, float* __restrict__ c1) {
  int f = blockIdx.x;
  float s0 = 0.f, s1 = 0.f;
  for (int d = threadIdx.x; d < 768; d += 256) {
    float e = enc_W[(long)f * 768 + d];
    s0 += e * b_dec[d];
    s1 += e * w[d];
  }
  float r0 = blk_reduce(s0);
  float r1 = blk_reduce(s1);
  if (threadIdx.x == 0) { c0[f] = enc_b[f] - r0; c1[f] = r1; }
}

// ---------------- GEMM (BT form: C[m,n] = sum_k A[m,k]*B[n,k]) ----------------
// BK=64, XOR-swizzled staging. K (and kChunk) must be multiples of 64.
// mode 0: bf16 store; mode 1: *= bf16 mask, bf16 store;
// mode 2: split-K fp32 overwrite; mode 3: split-K fp32 read-accumulate
__global__ __launch_bounds__(256)
void gemm_bt(const bf16* __restrict__ A, const bf16* __restrict__ B, void* __restrict__ Cv,
             int M, int N, int K,
             long lda, long ldb, long ldc,
             int batchH,
             long sa_b, long sa_h, long sb_b, long sb_h, long sc_b, long sc_h,
             int mode, int kChunk,
             const bf16* __restrict__ mask, long mask_ld)
{
  __shared__ __align__(16) bf16 Asm[128 * 64];
  __shared__ __align__(16) bf16 Bsm[128 * 64];

  const int t = threadIdx.x;

  // bijective XCD-aware remap of the (x,y) tile id (m204 formula)
  const int nbx = gridDim.x, nby = gridDim.y;
  const int nxy = nbx * nby;
  int orig = blockIdx.x + nbx * blockIdx.y;
  int qq = nxy >> 3, rr = nxy & 7;
  int xcd = orig & 7, lid = orig >> 3;
  int swz = (xcd < rr) ? (xcd * (qq + 1) + lid)
                       : (rr * (qq + 1) + (xcd - rr) * qq + lid);
  const int m0 = (swz % nby) * 128;
  const int n0 = (swz / nby) * 128;

  long aoff, boff, coff;
  int k0, k1;
  if (mode >= 2) {
    int z = blockIdx.z;
    aoff = 0; boff = 0;
    coff = (long)z * (long)M * ldc;
    k0 = z * kChunk; k1 = k0 + kChunk; if (k1 > K) k1 = K;
  } else {
    int z = blockIdx.z;
    int bb = z / batchH, hh = z - bb * batchH;
    aoff = (long)bb * sa_b + (long)hh * sa_h;
    boff = (long)bb * sb_b + (long)hh * sb_h;
    coff = (long)bb * sc_b + (long)hh * sc_h;
    k0 = 0; k1 = K;
  }

  const bf16* Ab = A + aoff + (long)m0 * lda;
  const bf16* Bb = B + boff + (long)n0 * ldb;

  const int r0 = t >> 3;           // 0..31 (staging row within 32-row group)
  const int g8 = t & 7;            // staging col-group (LDS slot)

  const int L = t & 63, w = t >> 6;
  const int wm = (w & 1) * 64, wn = (w >> 1) * 64;
  const int r16 = L & 15, q = L >> 4;

  f32x4 acc[4][4];
#pragma unroll
  for (int i = 0; i < 4; i++)
#pragma unroll
    for (int j = 0; j < 4; j++) acc[i][j] = (f32x4){0.f, 0.f, 0.f, 0.f};

  for (int kt = k0; kt < k1; kt += 64) {
#pragma unroll
    for (int j = 0; j < 4; j++) {
      int row = j * 32 + r0;
      int sc = ((g8 ^ (row & 7)) << 3);      // source col swizzle
      gld16(Ab + (long)row * lda + (kt + sc), &Asm[j * 2048 + t * 8]);
      gld16(Bb + (long)row * ldb + (kt + sc), &Bsm[j * 2048 + t * 8]);
    }
    __syncthreads();

#pragma unroll
    for (int h2 = 0; h2 < 2; h2++) {
      bf16x8 af[4], bfr[4];
#pragma unroll
      for (int i = 0; i < 4; i++) {
        int ra = wm + i * 16 + r16;
        af[i]  = *(const bf16x8*)&Asm[ra * 64 + ((((h2 << 2) + q) ^ (ra & 7)) << 3)];
        int rb = wn + i * 16 + r16;
        bfr[i] = *(const bf16x8*)&Bsm[rb * 64 + ((((h2 << 2) + q) ^ (rb & 7)) << 3)];
      }
#pragma unroll
      for (int mi = 0; mi < 4; mi++)
#pragma unroll
        for (int ni = 0; ni < 4; ni++)
          acc[mi][ni] = __builtin_amdgcn_mfma_f32_16x16x32_bf16(af[mi], bfr[ni], acc[mi][ni], 0, 0, 0);
    }
    __syncthreads();
  }

  if (mode >= 2) {
    float* C = (float*)Cv;
#pragma unroll
    for (int mi = 0; mi < 4; mi++)
#pragma unroll
      for (int ni = 0; ni < 4; ni++)
#pragma unroll
        for (int r = 0; r < 4; r++) {
          int gm = m0 + wm + mi * 16 + q * 4 + r;
          int gn = n0 + wn + ni * 16 + r16;
          long idx = coff + (long)gm * ldc + gn;
          float v = acc[mi][ni][r];
          if (mode == 3) v += C[idx];
          C[idx] = v;
        }
  } else {
    bf16* C = (bf16*)Cv;
#pragma unroll
    for (int mi = 0; mi < 4; mi++)
#pragma unroll
      for (int ni = 0; ni < 4; ni++)
#pragma unroll
        for (int r = 0; r < 4; r++) {
          int gm = m0 + wm + mi * 16 + q * 4 + r;
          int gn = n0 + wn + ni * 16 + r16;
          float v = acc[mi][ni][r];
          if (mode == 1) v *= (float)mask[(long)gm * mask_ld + gn];
          C[coff + (long)gm * ldc + gn] = (bf16)v;
        }
  }
}

// ------------- pipelined split-K GEMM (final GEMM only) ----------------------
// C[m,n] (+)= sum_k A[m,k]*B[n,k], fp32 C. 512 threads = 8 waves (2M x 4N),
// per-wave 64x32 output. BK=64. 4 LDS buffers (128 KiB), depth-3 prefetch,
// counted vmcnt (8/4/0), ONE barrier per K-step. K, kChunk multiples of 64.
// mode 2 = overwrite, 3 = read-accumulate.
__global__ __launch_bounds__(512)
void gemm_fp(const bf16* __restrict__ A, const bf16* __restrict__ B,
             float* __restrict__ C,
             int M, int N, int K, long lda, long ldb, long ldc,
             int mode, int kChunk)
{
  __shared__ __align__(16) bf16 SM[4][2][8192];   // [buf][A|B][128*64]

  const int t = threadIdx.x;

  // bijective XCD swizzle over the (x,y) tile plane
  const int nbx = gridDim.x, nby = gridDim.y;
  const int nxy = nbx * nby;
  int orig = blockIdx.x + nbx * blockIdx.y;
  int qq = nxy >> 3, rr = nxy & 7;
  int xcd = orig & 7, lid = orig >> 3;
  int swz = (xcd < rr) ? (xcd * (qq + 1) + lid)
                       : (rr * (qq + 1) + (xcd - rr) * qq + lid);
  const int m0 = (swz % nby) * 128;
  const int n0 = (swz / nby) * 128;

  const int z = blockIdx.z;
  const long coff = (long)z * (long)M * ldc;
  int k0 = z * kChunk, k1 = k0 + kChunk; if (k1 > K) k1 = K;
  const int NT = (k1 > k0) ? (k1 - k0) >> 6 : 0;

  const bf16* Ab = A + (long)m0 * lda + k0;
  const bf16* Bb = B + (long)n0 * ldb + k0;

  const int sr = t >> 3;           // 0..63 staging row within 64-row group
  const int g8 = t & 7;            // staging col-group (LDS slot)

  const int L = t & 63, w = t >> 6;          // 8 waves
  const int wm = (w & 1) * 64;               // 2 waves over M (128)
  const int wn = (w >> 1) * 32;              // 4 waves over N (128)
  const int r16 = L & 15, q = L >> 4;

  f32x4 acc[4][2];
#pragma unroll
  for (int i = 0; i < 4; i++)
#pragma unroll
    for (int j = 0; j < 2; j++) acc[i][j] = (f32x4){0.f, 0.f, 0.f, 0.f};

  // stage K-tile tt into buffer buf: 4 gld16 per thread (2 A rounds, 2 B)
  auto stage = [&](int tt, int buf) {
    const bf16* Ap = Ab + (long)tt * 64;
    const bf16* Bp = Bb + (long)tt * 64;
#pragma unroll
    for (int j = 0; j < 2; j++) {
      int row = j * 64 + sr;
      int sc = ((g8 ^ (row & 7)) << 3);
      gld16(Ap + (long)row * lda + sc, &SM[buf][0][j * 4096 + t * 8]);
    }
#pragma unroll
    for (int j = 0; j < 2; j++) {
      int row = j * 64 + sr;
      int sc = ((g8 ^ (row & 7)) << 3);
      gld16(Bp + (long)row * ldb + sc, &SM[buf][1][j * 4096 + t * 8]);
    }
  };

  if (NT >= 1) stage(0, 0);
  if (NT >= 2) stage(1, 1);
  if (NT >= 3) stage(2, 2);

  for (int tt = 0; tt < NT; tt++) {
    // groups younger than tt currently issued: min(2, NT-1-tt) x 4 loads
    int rem = NT - 1 - tt;
    if (rem >= 2)      asm volatile("s_waitcnt vmcnt(8)" ::: "memory");
    else if (rem == 1) asm volatile("s_waitcnt vmcnt(4)" ::: "memory");
    else               asm volatile("s_waitcnt vmcnt(0)" ::: "memory");
    __builtin_amdgcn_s_barrier();

    if (tt + 3 < NT) stage(tt + 3, (tt + 3) & 3);

    const bf16* As = &SM[tt & 3][0][0];
    const bf16* Bs = &SM[tt & 3][1][0];
#pragma unroll
    for (int h2 = 0; h2 < 2; h2++) {
      bf16x8 af[4], bfr[2];
#pragma unroll
      for (int i = 0; i < 4; i++) {
        int ra = wm + i * 16 + r16;
        af[i]  = *(const bf16x8*)&As[ra * 64 + ((((h2 << 2) + q) ^ (ra & 7)) << 3)];
      }
#pragma unroll
      for (int i = 0; i < 2; i++) {
        int rb = wn + i * 16 + r16;
        bfr[i] = *(const bf16x8*)&Bs[rb * 64 + ((((h2 << 2) + q) ^ (rb & 7)) << 3)];
      }
#pragma unroll
      for (int mi = 0; mi < 4; mi++)
#pragma unroll
        for (int ni = 0; ni < 2; ni++)
          acc[mi][ni] = __builtin_amdgcn_mfma_f32_16x16x32_bf16(af[mi], bfr[ni], acc[mi][ni], 0, 0, 0);
    }
  }

#pragma unroll
  for (int mi = 0; mi < 4; mi++)
#pragma unroll
    for (int ni = 0; ni < 2; ni++)
#pragma unroll
      for (int r = 0; r < 4; r++) {
        int gm = m0 + wm + mi * 16 + q * 4 + r;
        int gn = n0 + wn + ni * 16 + r16;
        long idx = coff + (long)gm * ldc + gn;
        float v = acc[mi][ni][r];
        if (mode == 3) v += C[idx];
        C[idx] = v;
      }
}

// ---------------- final reduce + bias epilogue (fp32 out, float4) ------------
__global__ void k_out(const float* __restrict__ Cp, const float* __restrict__ c0,
                      const float* __restrict__ c1, const float* __restrict__ invln,
                      float* __restrict__ out, int nsplit) {
  int i4 = blockIdx.x * 256 + threadIdx.x;          // 524288
  long i = (long)i4 * 4;
  int n = (int)(i & 2047), m = (int)(i >> 11);
  float4 v = *(const float4*)(Cp + i);
  for (int z = 1; z < nsplit; z++) {
    float4 u = *(const float4*)(Cp + i + (long)z * 2097152);
    v.x += u.x; v.y += u.y; v.z += u.z; v.w += u.w;
  }
  float il = invln[m];
  float4 a = *(const float4*)(c0 + n);
  float4 b = *(const float4*)(c1 + n);
  v.x += a.x + b.x * il;
  v.y += a.y + b.y * il;
  v.z += a.z + b.z * il;
  v.w += a.w + b.w * il;
  *(float4*)(out + i) = v;
}

// ---------------- host ----------------

extern "C" void kernel_launch(void* const* d_in, const int* in_sizes, int n_in,
                              void* d_out, int out_size, void* d_ws, size_t ws_size,
                              hipStream_t stream) {
  (void)out_size;
  float* out = (float*)d_out;

  // ---- resolve inputs by size (order-agnostic) ----
  int iresid = -1, iln = -1, iprobs = -1, iencb = -1, ipruned = -1, imask = -1;
  int iwo = -1, iwv = -1, iencw = -1, iupdw = -1, ibdec = -1, iupb = -1;
  for (int i = 0; i < n_in; i++) {
    switch (in_sizes[i]) {
      case 786432:  iresid  = i; break;
      case 1024:    iln     = i; break;
      case 3145728: iprobs  = i; break;
      case 2048:    iencb   = i; break;
      case 2097152: ipruned = i; break;
      case 4194304: imask   = i; break;
      case 589824:  if (iwo   < 0) iwo   = i; else iwv   = i; break;
      case 1572864: if (iencw < 0) iencw = i; else iupdw = i; break;
      case 768:     if (ibdec < 0) ibdec = i; else iupb  = i; break;
      default: break;
    }
  }
  bool ok = n_in == 12 && iresid >= 0 && iln >= 0 && iprobs >= 0 && iencb >= 0 &&
            ipruned >= 0 && imask >= 0 && iwo >= 0 && iwv >= 0 && iencw >= 0 &&
            iupdw >= 0 && ibdec >= 0 && iupb >= 0;
  if (!ok) { k_sentinel<<<8192, 256, 0, stream>>>(out); return; }

  const float* resid = (const float*)d_in[iresid];
  const float* lns   = (const float*)d_in[iln];
  const float* probs = (const float*)d_in[iprobs];
  const float* W_O   = (const float*)d_in[iwo];
  const float* W_V   = (const float*)d_in[iwv];
  const float* enc_W = (const float*)d_in[iencw];
  const float* enc_b = (const float*)d_in[iencb];
  const float* b_dec = (const float*)d_in[ibdec];
  const float* updW  = (const float*)d_in[iupdw];
  const float* up_b  = (const float*)d_in[iupb];
  const float* pruned= (const float*)d_in[ipruned];
  const int*   cmask = (const int*)d_in[imask];

  // ---- workspace sizing ----
  auto pad = [](size_t b) -> size_t { return (b + 255) & ~(size_t)255; };
  // overlay prep buffers (ALL dead before the first final-GEMM dispatch):
  const size_t prepB = pad(2359296) + pad(2359296) + pad(3145728) + pad(1572864) +
                       pad(3145728) + pad(1179648) + pad(3145728) + pad(18874368);
  // persistent (live across the g-loop): G_t, Ut, E1, probsT, maskb + smalls
  const size_t persB = pad(6291456) + pad(4194304) + pad(6291456) + pad(6291456) +
                       pad(8388608) + pad(4096) + pad(3072) + pad(3072) +
                       pad(8192) + pad(8192);
  auto needB = [&](int g, int ns) -> size_t {
    size_t cp = (size_t)ns * 8388608;
    size_t ov = prepB > cp ? prepB : cp;
    long KA = (long)g * 2048 + 768;
    size_t ab = pad((size_t)1024 * KA * 2) + pad((size_t)2048 * KA * 2);
    return ov + persB + ab + (2ull << 20);   // 2MiB slack
  };
  const int cgs[14] = {12, 12, 12, 6, 6, 4, 3, 2, 2, 1, 1, 1, 1, 1};
  const int cns[14] = { 2,  4, 8, 4, 2, 4, 4, 4, 2, 8, 4, 2, 2, 1};
  int gs = 0, nsplit = 0;
  for (int ci = 0; ci < 14; ci++) {
    if (needB(cgs[ci], cns[ci]) <= ws_size) { gs = cgs[ci]; nsplit = cns[ci]; break; }
  }
  if (gs == 0) { gs = 1; nsplit = 1; }

  const long KA = (long)gs * 2048 + 768;     // A_g/B_g leading dim (K incl. tail)

  char* p = (char*)d_ws;
  auto alloc = [&](size_t bytes) -> char* {
    char* r = p; p += (bytes + 255) & ~(size_t)255; return r;
  };
  // -- overlay region: prep buffers, later reused as Cpart --
  char* overlayBase = p;
  bf16*  WOb    = (bf16*)alloc(12ull * 128 * 768 * 2);
  bf16*  WVt    = (bf16*)alloc(12ull * 128 * 768 * 2);
  bf16*  updWt  = (bf16*)alloc(2048ull * 768 * 2);
  bf16*  Xb     = (bf16*)alloc(1024ull * 768 * 2);
  bf16*  encWb  = (bf16*)alloc(2048ull * 768 * 2);
  bf16*  W_Ot   = (bf16*)alloc(12ull * 768 * 64 * 2);
  bf16*  T1     = (bf16*)alloc(12ull * 1024 * 128 * 2);
  bf16*  T3     = (bf16*)alloc(4ull * 768 * 3072 * 2);
  {
    size_t used = (size_t)(p - overlayBase);
    size_t cp = (size_t)nsplit * 8388608;
    p = overlayBase + (used > cp ? used : cp);
  }
  float* Cpart  = (float*)overlayBase;       // aliases dead prep buffers
  // -- persistent region --
  bf16*  G_t    = (bf16*)alloc(12ull * 2048 * 128 * 2);
  bf16*  Ut     = (bf16*)alloc(4ull * 2048 * 256 * 2);
  bf16*  E1     = (bf16*)alloc(12ull * 2048 * 128 * 2);
  bf16*  probsT = (bf16*)alloc(4ull * 256 * 3072 * 2);
  bf16*  maskb  = (bf16*)alloc(2048ull * 2048 * 2);
  float* invln  = (float*)alloc(1024 * 4);
  float* t_hk   = (float*)alloc(768 * 4);
  float* wv     = (float*)alloc(768 * 4);
  float* c0     = (float*)alloc(2048 * 4);
  float* c1     = (float*)alloc(2048 * 4);
  bf16*  A_g    = (bf16*)alloc((size_t)1024 * KA * 2);
  bf16*  B_g    = (bf16*)alloc((size_t)2048 * KA * 2);

  // ---- prep ----
  k_invln<<<4, 256, 0, stream>>>(lns, invln);
  k_cast4<<<1536, 256, 0, stream>>>(enc_W, encWb, 393216);
  k_probsT<<<3072, 256, 0, stream>>>(probs, probsT);
  k_maskb<<<4096, 256, 0, stream>>>(cmask, maskb, 1048576);
  k_WO<<<4608, 256, 0, stream>>>(W_O, WOb);
  k_WVtT<<<dim3(4, 24, 12), 256, 0, stream>>>(W_V, WVt);
  k_WOt<<<dim3(2, 24, 12), 256, 0, stream>>>(W_O, W_Ot);
  k_updWtT<<<dim3(64, 24), 256, 0, stream>>>(updW, updWt);
  k_Xb<<<768, 256, 0, stream>>>(resid, invln, Xb);
  k_UtT<<<dim3(64, 8, 4), 256, 0, stream>>>(pruned, invln, Ut);
  k_bias_t<<<768, 256, 0, stream>>>(W_V, up_b, t_hk);
  k_bias_w<<<768, 256, 0, stream>>>(W_O, t_hk, wv);
  k_bias_c<<<2048, 256, 0, stream>>>(enc_W, enc_b, b_dec, wv, c0, c1);

  // Merged E1 + G_t (z = 24, bb selects the problem via pointer-diff strides):
  //   bb=0: E1[h][f][k]  = encWb[f,o] . WOb[h][k][o]
  //   bb=1: G_t[h][u][k] = updWt[u,i] . WVt[h][k][i]
  gemm_bt<<<dim3(1, 16, 24), 256, 0, stream>>>(
      encWb, WOb, E1, 2048, 128, 768,
      768, 768, 128, 12,
      (long)(updWt - encWb), 0,
      (long)(WVt - WOb), (long)128 * 768,
      (long)(G_t - E1), (long)2048 * 128,
      0, 0, nullptr, 0);

  // ---- init path: T1 -> T3 -> S (appended into A_g K-tail) ----
  // T1[h][bs][k128] = Xb[bs,i] . WVt[h][k][i]   M=1024 N=128 K=768 (z=h)
  gemm_bt<<<dim3(1, 8, 12), 256, 0, stream>>>(
      Xb, WVt, T1, 1024, 128, 768,
      768, 768, 128, 12,
      0, 0, 0, (long)128 * 768, 0, (long)1024 * 128,
      0, 0, nullptr, 0);

  // T3[b][o][h*256+s] = W_Ot[h][o][k] . T1[h][b*256+s][k]   M=768 N=256 K=64
  // z=(b,h) via batchH=12
  gemm_bt<<<dim3(2, 6, 48), 256, 0, stream>>>(
      W_Ot, T1, T3, 768, 256, 64,
      64, 128, 3072, 12,
      0, (long)768 * 64, (long)256 * 128, (long)1024 * 128, 2359296, 256,
      0, 0, nullptr, 0);

  // S[b][q][o] = probsT[b][q][hs] . T3[b][o][hs]  -> A_g[:, gs*2048 .. +768]
  // M=256 N=768 K=3072 (z=b)
  gemm_bt<<<dim3(6, 2, 4), 256, 0, stream>>>(
      probsT, T3, A_g + (long)gs * 2048, 256, 768, 3072,
      3072, 3072, KA, 1,
      786432, 0, 2359296, 0, 256 * KA, 0,
      0, 0, nullptr, 0);

  // B_g K-tail: enc_W columns (so S @ enc_W^T rides inside the final GEMM)
  k_append<<<768, 256, 0, stream>>>(encWb, B_g + (long)gs * 2048, KA);

  // ---- head-group loop (single iteration when gs==12) ----
  for (int g = 0; g < 12 / gs; g++) {
    // V_g: B_g[f][hh*2048+u] = maskb[f,u] * (E1_h[f,k] . G_t_h[u,k])  K=128
    gemm_bt<<<dim3(16, 16, gs), 256, 0, stream>>>(
        E1 + (long)g * gs * 2048 * 128, G_t + (long)g * gs * 2048 * 128, B_g,
        2048, 2048, 128,
        128, 128, KA, gs,
        0, (long)2048 * 128, 0, (long)2048 * 128, 0, 2048,
        1, 0, maskb, 2048);

    // PU_g: A_g[b*256+q][hh*2048+u] = probsT[b][q][(g*gs+hh)*256 + s] . Ut[b][u][s]
    // M=256 N=2048 K=256, z=(b,hh) via batchH=gs
    gemm_bt<<<dim3(16, 2, 4 * gs), 256, 0, stream>>>(
        probsT + (long)g * gs * 256, Ut, A_g,
        256, 2048, 256,
        3072, 256, KA, gs,
        786432, 256, (long)2048 * 256, 0, 256 * KA, 2048,
        0, 0, nullptr, 0);

    // Cpart (+)= A_g[bq,k] . B_g[f,k]  -- deep-pipelined kernel
    // g==0 includes the 768-col [S | enc_W] tail; g>0 only the gs*2048 cols.
    int Kthis = (g == 0) ? (int)KA : gs * 2048;
    int kc = ((Kthis / nsplit + 63) / 64) * 64;
    gemm_fp<<<dim3(16, 8, nsplit), 512, 0, stream>>>(
        A_g, B_g, Cpart,
        1024, 2048, Kthis,
        KA, KA, 2048,
        (g == 0) ? 2 : 3, kc);
  }

  // out[b,q,f] = fp32( sum_z Cpart + c0[f] + c1[f]*invln[bq] )
  k_out<<<2048, 256, 0, stream>>>(Cpart, c0, c1, invln, out, nsplit);
}

// Round 4
// 495.750 us; speedup vs baseline: 1.2092x; 1.0202x over previous
//
#include <hip/hip_runtime.h>
#include <hip/hip_bf16.h>
#include <stdint.h>

typedef __bf16 bf16;
typedef __bf16 bf16x8 __attribute__((ext_vector_type(8)));
typedef __bf16 bf16x4 __attribute__((ext_vector_type(4)));
typedef float f32x4 __attribute__((ext_vector_type(4)));

#define AS1 __attribute__((address_space(1)))
#define AS3 __attribute__((address_space(3)))

// B=4, S=256, H=12, DH=64(pad 128), D=768, FD=2048, FU=2048
// R23 (this round): R20-R22 finals all saturate ~10-12.5 TB/s of L2/L3->CU
// supply (flow = ntiles*(BM+BN)*K*2B); the final GEMM is SUPPLY-bound, not
// schedule-bound. Fix = bigger tile: gemm_fp2 BM=BN=256 halves flow to
// 0.83GB (0.52GB with per-XCD B-panel dedup). 512thr/8 waves (2Mx4N,
// 128x64/wave), BK=64, 2-buffer dbuf (128KiB LDS), counted vmcnt(8),
// nsplit=8 -> grid (8,4,8)=256 blocks = 1/CU.

__device__ __forceinline__ void gld16(const bf16* g, bf16* l) {
  __builtin_amdgcn_global_load_lds((AS1 void*)g, (AS3 void*)l, 16, 0, 0);
}

__global__ void k_sentinel(float* __restrict__ out) {
  int i = blockIdx.x * 256 + threadIdx.x;
  if (i < 2097152) out[i] = 1048576.0f;
}

// ---------------- prep kernels ----------------

__global__ void k_invln(const float* __restrict__ ln, float* __restrict__ invln) {
  int i = blockIdx.x * 256 + threadIdx.x;
  if (i < 1024) invln[i] = 1.0f / ln[i];
}

// vectorized fp32 -> bf16 cast, n4 = n/4
__global__ void k_cast4(const float* __restrict__ s, bf16* __restrict__ d, int n4) {
  int i = blockIdx.x * 256 + threadIdx.x;
  if (i < n4) {
    float4 v = *(const float4*)(s + (long)i * 4);
    bf16x4 o;
    o[0] = (bf16)v.x; o[1] = (bf16)v.y; o[2] = (bf16)v.z; o[3] = (bf16)v.w;
    *(bf16x4*)(d + (long)i * 4) = o;
  }
}

// int32 0/1 mask -> bf16, n4 = n/4
__global__ void k_maskb(const int* __restrict__ m, bf16* __restrict__ d, int n4) {
  int i = blockIdx.x * 256 + threadIdx.x;
  if (i < n4) {
    int4 v = *(const int4*)(m + (long)i * 4);
    bf16x4 o;
    o[0] = (bf16)(float)v.x; o[1] = (bf16)(float)v.y;
    o[2] = (bf16)(float)v.z; o[3] = (bf16)(float)v.w;
    *(bf16x4*)(d + (long)i * 4) = o;
  }
}

// probsT[b][q][h*256+s] = bf16(probs[b,h,q,s])   (contiguous in s both sides)
__global__ void k_probsT(const float* __restrict__ probs, bf16* __restrict__ pT) {
  int i = blockIdx.x * 256 + threadIdx.x;   // 786432 vec4s
  if (i < 786432) {
    long idx = (long)i * 4;
    int s  = (int)(idx & 255);
    int q  = (int)((idx >> 8) & 255);
    int hb = (int)(idx >> 16);
    int h = hb % 12, b = hb / 12;
    float4 v = *(const float4*)(probs + idx);
    bf16x4 o;
    o[0] = (bf16)v.x; o[1] = (bf16)v.y; o[2] = (bf16)v.z; o[3] = (bf16)v.w;
    *(bf16x4*)(pT + (long)b * 786432 + (long)q * 3072 + h * 256 + s) = o;
  }
}

__global__ void k_WO(const float* __restrict__ W_O, bf16* __restrict__ WOb) {
  int i = blockIdx.x * 256 + threadIdx.x;           // 12*128*768
  int o = i % 768, r = (i / 768) & 127, h = i / (768 * 128);
  WOb[i] = (r < 64) ? (bf16)W_O[(long)(h * 64 + r) * 768 + o] : (bf16)0.0f;
}

// WVt[h][k<128][i<768] = W_V[h,i,k]  (tiled transpose, zero-pad k>=64)
__global__ void k_WVtT(const float* __restrict__ wv, bf16* __restrict__ WVt) {
  __shared__ float tile[32][33];
  int h = blockIdx.z;                 // 12
  int k0 = blockIdx.x * 32;           // 0..96
  int i0 = blockIdx.y * 32;           // 24 tiles
  int lane = threadIdx.x & 31, rg = threadIdx.x >> 5;
  if (k0 < 64) {
    for (int r = rg; r < 32; r += 8)
      tile[r][lane] = wv[((long)(h * 768 + i0 + r)) * 64 + k0 + lane];
    __syncthreads();
    for (int r = rg; r < 32; r += 8)
      WVt[((long)h * 128 + k0 + r) * 768 + i0 + lane] = (bf16)tile[lane][r];
  } else {
    for (int r = rg; r < 32; r += 8)
      WVt[((long)h * 128 + k0 + r) * 768 + i0 + lane] = (bf16)0.0f;
  }
}

// W_Ot[h][o][k64] = W_O[h,k,o]  (tiled transpose)
__global__ void k_WOt(const float* __restrict__ wo, bf16* __restrict__ W_Ot) {
  __shared__ float tile[32][33];
  int h = blockIdx.z;                 // 12
  int k0 = blockIdx.x * 32;           // 0..32
  int o0 = blockIdx.y * 32;           // 24 tiles
  int lane = threadIdx.x & 31, rg = threadIdx.x >> 5;
  for (int r = rg; r < 32; r += 8)
    tile[r][lane] = wo[((long)(h * 64 + k0 + r)) * 768 + o0 + lane];
  __syncthreads();
  for (int r = rg; r < 32; r += 8)
    W_Ot[((long)(h * 768 + o0 + r)) * 64 + k0 + lane] = (bf16)tile[lane][r];
}

// updWt[u][i] = up_dec_W[i][u]  (tiled transpose)
__global__ void k_updWtT(const float* __restrict__ u, bf16* __restrict__ d) {
  __shared__ float tile[32][33];
  int u0 = blockIdx.x * 32;           // 64 tiles
  int i0 = blockIdx.y * 32;           // 24 tiles
  int lane = threadIdx.x & 31, rg = threadIdx.x >> 5;
  for (int r = rg; r < 32; r += 8)
    tile[r][lane] = u[((long)(i0 + r)) * 2048 + u0 + lane];
  __syncthreads();
  for (int r = rg; r < 32; r += 8)
    d[((long)(u0 + r)) * 768 + i0 + lane] = (bf16)tile[lane][r];
}

// Xb[b*256+s][d] = resid[b,s,d] * invln (row-major bf16, no transpose)
__global__ void k_Xb(const float* __restrict__ resid, const float* __restrict__ invln,
                     bf16* __restrict__ Xb) {
  int i = blockIdx.x * 256 + threadIdx.x;   // 196608 vec4s
  if (i < 196608) {
    long idx = (long)i * 4;
    float il = invln[idx / 768];            // 4|768 so chunk never straddles rows
    float4 v = *(const float4*)(resid + idx);
    bf16x4 o;
    o[0] = (bf16)(v.x * il); o[1] = (bf16)(v.y * il);
    o[2] = (bf16)(v.z * il); o[3] = (bf16)(v.w * il);
    *(bf16x4*)(Xb + idx) = o;
  }
}

// Ut[b][u][s] = pruned[b,s,u] * invln  (tiled transpose)
__global__ void k_UtT(const float* __restrict__ pr, const float* __restrict__ invln,
                      bf16* __restrict__ Ut) {
  __shared__ float tile[32][33];
  int b = blockIdx.z, u0 = blockIdx.x * 32, s0 = blockIdx.y * 32;  // (64, 8, 4)
  int lane = threadIdx.x & 31, rg = threadIdx.x >> 5;
  for (int r = rg; r < 32; r += 8) {
    int s = s0 + r;
    tile[r][lane] = pr[((long)(b * 256 + s)) * 2048 + u0 + lane] * invln[b * 256 + s];
  }
  __syncthreads();
  for (int r = rg; r < 32; r += 8)
    Ut[((long)b * 2048 + u0 + r) * 256 + s0 + lane] = (bf16)tile[lane][r];
}

// append enc_W (bf16) as the 768-column K-tail of B_g
__global__ void k_append(const bf16* __restrict__ encWb, bf16* __restrict__ Bt, long ldb) {
  int i = blockIdx.x * 256 + threadIdx.x;   // 196608 vec8s
  if (i < 196608) {
    long idx = (long)i * 8;
    int f = (int)(idx / 768), d = (int)(idx % 768);
    *(bf16x8*)(Bt + (long)f * ldb + d) = *(const bf16x8*)(encWb + idx);
  }
}

// ---------------- bias chain (fp32, block-parallel) ----------------

__device__ __forceinline__ float blk_reduce(float s) {
  __shared__ float red[256];
  red[threadIdx.x] = s; __syncthreads();
  for (int o = 128; o > 0; o >>= 1) {
    if ((int)threadIdx.x < o) red[threadIdx.x] += red[threadIdx.x + o];
    __syncthreads();
  }
  float r = red[0]; __syncthreads();
  return r;
}

__global__ void k_bias_t(const float* __restrict__ W_V, const float* __restrict__ up_b,
                         float* __restrict__ t_hk) {
  int j = blockIdx.x, h = j >> 6, k = j & 63;
  float s = 0.f;
  for (int m = threadIdx.x; m < 768; m += 256)
    s += W_V[((long)(h * 768 + m)) * 64 + k] * up_b[m];
  float r = blk_reduce(s);
  if (threadIdx.x == 0) t_hk[j] = r;
}

__global__ void k_bias_w(const float* __restrict__ W_O, const float* __restrict__ t_hk,
                         float* __restrict__ w) {
  int d = blockIdx.x;
  float s = 0.f;
  for (int j = threadIdx.x; j < 768; j += 256)
    s += W_O[(long)j * 768 + d] * t_hk[j];
  float r = blk_reduce(s);
  if (threadIdx.x == 0) w[d] = r;
}

__global__ void k_bias_c(const float* __restrict__ enc_W, const float* __restrict__ enc_b,
                         const float* __restrict__ b_dec, const float* __restrict__ w,
                         float* __restrict__ c0, float* __restrict__ c1) {
  int f = blockIdx.x;
  float s0 = 0.f, s1 = 0.f;
  for (int d = threadIdx.x; d < 768; d += 256) {
    float e = enc_W[(long)f * 768 + d];
    s0 += e * b_dec[d];
    s1 += e * w[d];
  }
  float r0 = blk_reduce(s0);
  float r1 = blk_reduce(s1);
  if (threadIdx.x == 0) { c0[f] = enc_b[f] - r0; c1[f] = r1; }
}

// ---------------- GEMM (BT form: C[m,n] = sum_k A[m,k]*B[n,k]) ----------------
// BK=64, XOR-swizzled staging. K (and kChunk) must be multiples of 64.
// mode 0: bf16 store; mode 1: *= bf16 mask, bf16 store;
// mode 2: split-K fp32 overwrite; mode 3: split-K fp32 read-accumulate
__global__ __launch_bounds__(256)
void gemm_bt(const bf16* __restrict__ A, const bf16* __restrict__ B, void* __restrict__ Cv,
             int M, int N, int K,
             long lda, long ldb, long ldc,
             int batchH,
             long sa_b, long sa_h, long sb_b, long sb_h, long sc_b, long sc_h,
             int mode, int kChunk,
             const bf16* __restrict__ mask, long mask_ld)
{
  __shared__ __align__(16) bf16 Asm[128 * 64];
  __shared__ __align__(16) bf16 Bsm[128 * 64];

  const int t = threadIdx.x;

  // bijective XCD-aware remap of the (x,y) tile id (m204 formula)
  const int nbx = gridDim.x, nby = gridDim.y;
  const int nxy = nbx * nby;
  int orig = blockIdx.x + nbx * blockIdx.y;
  int qq = nxy >> 3, rr = nxy & 7;
  int xcd = orig & 7, lid = orig >> 3;
  int swz = (xcd < rr) ? (xcd * (qq + 1) + lid)
                       : (rr * (qq + 1) + (xcd - rr) * qq + lid);
  const int m0 = (swz % nby) * 128;
  const int n0 = (swz / nby) * 128;

  long aoff, boff, coff;
  int k0, k1;
  if (mode >= 2) {
    int z = blockIdx.z;
    aoff = 0; boff = 0;
    coff = (long)z * (long)M * ldc;
    k0 = z * kChunk; k1 = k0 + kChunk; if (k1 > K) k1 = K;
  } else {
    int z = blockIdx.z;
    int bb = z / batchH, hh = z - bb * batchH;
    aoff = (long)bb * sa_b + (long)hh * sa_h;
    boff = (long)bb * sb_b + (long)hh * sb_h;
    coff = (long)bb * sc_b + (long)hh * sc_h;
    k0 = 0; k1 = K;
  }

  const bf16* Ab = A + aoff + (long)m0 * lda;
  const bf16* Bb = B + boff + (long)n0 * ldb;

  const int r0 = t >> 3;           // 0..31 (staging row within 32-row group)
  const int g8 = t & 7;            // staging col-group (LDS slot)

  const int L = t & 63, w = t >> 6;
  const int wm = (w & 1) * 64, wn = (w >> 1) * 64;
  const int r16 = L & 15, q = L >> 4;

  f32x4 acc[4][4];
#pragma unroll
  for (int i = 0; i < 4; i++)
#pragma unroll
    for (int j = 0; j < 4; j++) acc[i][j] = (f32x4){0.f, 0.f, 0.f, 0.f};

  for (int kt = k0; kt < k1; kt += 64) {
#pragma unroll
    for (int j = 0; j < 4; j++) {
      int row = j * 32 + r0;
      int sc = ((g8 ^ (row & 7)) << 3);      // source col swizzle
      gld16(Ab + (long)row * lda + (kt + sc), &Asm[j * 2048 + t * 8]);
      gld16(Bb + (long)row * ldb + (kt + sc), &Bsm[j * 2048 + t * 8]);
    }
    __syncthreads();

#pragma unroll
    for (int h2 = 0; h2 < 2; h2++) {
      bf16x8 af[4], bfr[4];
#pragma unroll
      for (int i = 0; i < 4; i++) {
        int ra = wm + i * 16 + r16;
        af[i]  = *(const bf16x8*)&Asm[ra * 64 + ((((h2 << 2) + q) ^ (ra & 7)) << 3)];
        int rb = wn + i * 16 + r16;
        bfr[i] = *(const bf16x8*)&Bsm[rb * 64 + ((((h2 << 2) + q) ^ (rb & 7)) << 3)];
      }
#pragma unroll
      for (int mi = 0; mi < 4; mi++)
#pragma unroll
        for (int ni = 0; ni < 4; ni++)
          acc[mi][ni] = __builtin_amdgcn_mfma_f32_16x16x32_bf16(af[mi], bfr[ni], acc[mi][ni], 0, 0, 0);
    }
    __syncthreads();
  }

  if (mode >= 2) {
    float* C = (float*)Cv;
#pragma unroll
    for (int mi = 0; mi < 4; mi++)
#pragma unroll
      for (int ni = 0; ni < 4; ni++)
#pragma unroll
        for (int r = 0; r < 4; r++) {
          int gm = m0 + wm + mi * 16 + q * 4 + r;
          int gn = n0 + wn + ni * 16 + r16;
          long idx = coff + (long)gm * ldc + gn;
          float v = acc[mi][ni][r];
          if (mode == 3) v += C[idx];
          C[idx] = v;
        }
  } else {
    bf16* C = (bf16*)Cv;
#pragma unroll
    for (int mi = 0; mi < 4; mi++)
#pragma unroll
      for (int ni = 0; ni < 4; ni++)
#pragma unroll
        for (int r = 0; r < 4; r++) {
          int gm = m0 + wm + mi * 16 + q * 4 + r;
          int gn = n0 + wn + ni * 16 + r16;
          float v = acc[mi][ni][r];
          if (mode == 1) v *= (float)mask[(long)gm * mask_ld + gn];
          C[coff + (long)gm * ldc + gn] = (bf16)v;
        }
  }
}

// ------------- 256x256-tile split-K GEMM (final GEMM only) -------------------
// C[m,n] (+)= sum_k A[m,k]*B[n,k], fp32 C. 512 threads = 8 waves (2M x 4N),
// per-wave 128x64 output. BK=64. 2 LDS buffers (128 KiB), depth-1 prefetch,
// counted vmcnt(8) (0 only at epilogue), 2 barriers per K-step.
// K, kChunk multiples of 64. mode 2 = overwrite, 3 = read-accumulate.
__global__ __launch_bounds__(512, 2)
void gemm_fp2(const bf16* __restrict__ A, const bf16* __restrict__ B,
              float* __restrict__ C,
              int M, int N, int K, long lda, long ldb, long ldc,
              int mode, int kChunk)
{
  __shared__ __align__(16) bf16 SM[2][2][16384];   // [buf][A|B][256*64]

  const int t = threadIdx.x;

  // bijective XCD swizzle: each XCD owns one 256-col B panel (n0 = xcd),
  // its co-resident blocks span m -> B panel dedups in that XCD's L2.
  const int nbx = gridDim.x, nby = gridDim.y;
  const int nxy = nbx * nby;
  int orig = blockIdx.x + nbx * blockIdx.y;
  int qq = nxy >> 3, rr = nxy & 7;
  int xcd = orig & 7, lid = orig >> 3;
  int swz = (xcd < rr) ? (xcd * (qq + 1) + lid)
                       : (rr * (qq + 1) + (xcd - rr) * qq + lid);
  const int m0 = (swz % nby) * 256;
  const int n0 = (swz / nby) * 256;

  const int z = blockIdx.z;
  const long coff = (long)z * (long)M * ldc;
  int k0 = z * kChunk, k1 = k0 + kChunk; if (k1 > K) k1 = K;
  const int NT = (k1 > k0) ? (k1 - k0) >> 6 : 0;

  const bf16* Ab = A + (long)m0 * lda + k0;
  const bf16* Bb = B + (long)n0 * ldb + k0;

  const int sr = t >> 3;           // 0..63 staging row within 64-row group
  const int g8 = t & 7;            // staging col-group (LDS slot)

  const int L = t & 63, w = t >> 6;          // 8 waves
  const int wm = (w & 1) * 128;              // 2 waves over M (256)
  const int wn = (w >> 1) * 64;              // 4 waves over N (256)
  const int r16 = L & 15, q = L >> 4;

  f32x4 acc[8][4];
#pragma unroll
  for (int i = 0; i < 8; i++)
#pragma unroll
    for (int j = 0; j < 4; j++) acc[i][j] = (f32x4){0.f, 0.f, 0.f, 0.f};

  // stage K-tile tt into buffer buf: 8 gld16 per thread (4 A rounds, 4 B)
  auto stage = [&](int tt, int buf) {
    const bf16* Ap = Ab + (long)tt * 64;
    const bf16* Bp = Bb + (long)tt * 64;
#pragma unroll
    for (int j = 0; j < 4; j++) {
      int row = j * 64 + sr;
      int sc = ((g8 ^ (row & 7)) << 3);
      gld16(Ap + (long)row * lda + sc, &SM[buf][0][j * 4096 + t * 8]);
    }
#pragma unroll
    for (int j = 0; j < 4; j++) {
      int row = j * 64 + sr;
      int sc = ((g8 ^ (row & 7)) << 3);
      gld16(Bp + (long)row * ldb + sc, &SM[buf][1][j * 4096 + t * 8]);
    }
  };

  if (NT >= 1) stage(0, 0);

  for (int tt = 0; tt < NT; tt++) {
    if (tt + 1 < NT) {
      stage(tt + 1, (tt + 1) & 1);           // prefetch next into other buffer
      asm volatile("s_waitcnt vmcnt(8)" ::: "memory");   // stage(tt) done
    } else {
      asm volatile("s_waitcnt vmcnt(0)" ::: "memory");   // epilogue drain
    }
    __builtin_amdgcn_s_barrier();            // buffer tt&1 ready for all waves

    const bf16* As = &SM[tt & 1][0][0];
    const bf16* Bs = &SM[tt & 1][1][0];
#pragma unroll
    for (int h2 = 0; h2 < 2; h2++) {
      bf16x8 af[8], bfr[4];
#pragma unroll
      for (int i = 0; i < 8; i++) {
        int ra = wm + i * 16 + r16;
        af[i]  = *(const bf16x8*)&As[ra * 64 + ((((h2 << 2) + q) ^ (ra & 7)) << 3)];
      }
#pragma unroll
      for (int i = 0; i < 4; i++) {
        int rb = wn + i * 16 + r16;
        bfr[i] = *(const bf16x8*)&Bs[rb * 64 + ((((h2 << 2) + q) ^ (rb & 7)) << 3)];
      }
#pragma unroll
      for (int mi = 0; mi < 8; mi++)
#pragma unroll
        for (int ni = 0; ni < 4; ni++)
          acc[mi][ni] = __builtin_amdgcn_mfma_f32_16x16x32_bf16(af[mi], bfr[ni], acc[mi][ni], 0, 0, 0);
    }
    __builtin_amdgcn_s_barrier();            // all waves done reading buf tt&1
  }

#pragma unroll
  for (int mi = 0; mi < 8; mi++)
#pragma unroll
    for (int ni = 0; ni < 4; ni++)
#pragma unroll
      for (int r = 0; r < 4; r++) {
        int gm = m0 + wm + mi * 16 + q * 4 + r;
        int gn = n0 + wn + ni * 16 + r16;
        long idx = coff + (long)gm * ldc + gn;
        float v = acc[mi][ni][r];
        if (mode == 3) v += C[idx];
        C[idx] = v;
      }
}

// ---------------- final reduce + bias epilogue (fp32 out, float4) ------------
__global__ void k_out(const float* __restrict__ Cp, const float* __restrict__ c0,
                      const float* __restrict__ c1, const float* __restrict__ invln,
                      float* __restrict__ out, int nsplit) {
  int i4 = blockIdx.x * 256 + threadIdx.x;          // 524288
  long i = (long)i4 * 4;
  int n = (int)(i & 2047), m = (int)(i >> 11);
  float4 v = *(const float4*)(Cp + i);
  for (int z = 1; z < nsplit; z++) {
    float4 u = *(const float4*)(Cp + i + (long)z * 2097152);
    v.x += u.x; v.y += u.y; v.z += u.z; v.w += u.w;
  }
  float il = invln[m];
  float4 a = *(const float4*)(c0 + n);
  float4 b = *(const float4*)(c1 + n);
  v.x += a.x + b.x * il;
  v.y += a.y + b.y * il;
  v.z += a.z + b.z * il;
  v.w += a.w + b.w * il;
  *(float4*)(out + i) = v;
}

// ---------------- host ----------------

extern "C" void kernel_launch(void* const* d_in, const int* in_sizes, int n_in,
                              void* d_out, int out_size, void* d_ws, size_t ws_size,
                              hipStream_t stream) {
  (void)out_size;
  float* out = (float*)d_out;

  // ---- resolve inputs by size (order-agnostic) ----
  int iresid = -1, iln = -1, iprobs = -1, iencb = -1, ipruned = -1, imask = -1;
  int iwo = -1, iwv = -1, iencw = -1, iupdw = -1, ibdec = -1, iupb = -1;
  for (int i = 0; i < n_in; i++) {
    switch (in_sizes[i]) {
      case 786432:  iresid  = i; break;
      case 1024:    iln     = i; break;
      case 3145728: iprobs  = i; break;
      case 2048:    iencb   = i; break;
      case 2097152: ipruned = i; break;
      case 4194304: imask   = i; break;
      case 589824:  if (iwo   < 0) iwo   = i; else iwv   = i; break;
      case 1572864: if (iencw < 0) iencw = i; else iupdw = i; break;
      case 768:     if (ibdec < 0) ibdec = i; else iupb  = i; break;
      default: break;
    }
  }
  bool ok = n_in == 12 && iresid >= 0 && iln >= 0 && iprobs >= 0 && iencb >= 0 &&
            ipruned >= 0 && imask >= 0 && iwo >= 0 && iwv >= 0 && iencw >= 0 &&
            iupdw >= 0 && ibdec >= 0 && iupb >= 0;
  if (!ok) { k_sentinel<<<8192, 256, 0, stream>>>(out); return; }

  const float* resid = (const float*)d_in[iresid];
  const float* lns   = (const float*)d_in[iln];
  const float* probs = (const float*)d_in[iprobs];
  const float* W_O   = (const float*)d_in[iwo];
  const float* W_V   = (const float*)d_in[iwv];
  const float* enc_W = (const float*)d_in[iencw];
  const float* enc_b = (const float*)d_in[iencb];
  const float* b_dec = (const float*)d_in[ibdec];
  const float* updW  = (const float*)d_in[iupdw];
  const float* up_b  = (const float*)d_in[iupb];
  const float* pruned= (const float*)d_in[ipruned];
  const int*   cmask = (const int*)d_in[imask];

  // ---- workspace sizing ----
  auto pad = [](size_t b) -> size_t { return (b + 255) & ~(size_t)255; };
  // overlay prep buffers (ALL dead before the first final-GEMM dispatch):
  const size_t prepB = pad(2359296) + pad(2359296) + pad(3145728) + pad(1572864) +
                       pad(3145728) + pad(1179648) + pad(3145728) + pad(18874368);
  // persistent (live across the g-loop): G_t, Ut, E1, probsT, maskb + smalls
  const size_t persB = pad(6291456) + pad(4194304) + pad(6291456) + pad(6291456) +
                       pad(8388608) + pad(4096) + pad(3072) + pad(3072) +
                       pad(8192) + pad(8192);
  auto needB = [&](int g, int ns) -> size_t {
    size_t cp = (size_t)ns * 8388608;
    size_t ov = prepB > cp ? prepB : cp;
    long KA = (long)g * 2048 + 768;
    size_t ab = pad((size_t)1024 * KA * 2) + pad((size_t)2048 * KA * 2);
    return ov + persB + ab + (2ull << 20);   // 2MiB slack
  };
  // prefer gs=12 (one final GEMM) + nsplit=8 (grid (8,4,8)=256 blocks = 1/CU)
  const int cgs[14] = {12, 12, 12, 6, 6, 4, 3, 2, 2, 1, 1, 1, 1, 1};
  const int cns[14] = { 8,  4, 2, 8, 4, 4, 4, 4, 2, 8, 4, 2, 2, 1};
  int gs = 0, nsplit = 0;
  for (int ci = 0; ci < 14; ci++) {
    if (needB(cgs[ci], cns[ci]) <= ws_size) { gs = cgs[ci]; nsplit = cns[ci]; break; }
  }
  if (gs == 0) { gs = 1; nsplit = 1; }

  const long KA = (long)gs * 2048 + 768;     // A_g/B_g leading dim (K incl. tail)

  char* p = (char*)d_ws;
  auto alloc = [&](size_t bytes) -> char* {
    char* r = p; p += (bytes + 255) & ~(size_t)255; return r;
  };
  // -- overlay region: prep buffers, later reused as Cpart --
  char* overlayBase = p;
  bf16*  WOb    = (bf16*)alloc(12ull * 128 * 768 * 2);
  bf16*  WVt    = (bf16*)alloc(12ull * 128 * 768 * 2);
  bf16*  updWt  = (bf16*)alloc(2048ull * 768 * 2);
  bf16*  Xb     = (bf16*)alloc(1024ull * 768 * 2);
  bf16*  encWb  = (bf16*)alloc(2048ull * 768 * 2);
  bf16*  W_Ot   = (bf16*)alloc(12ull * 768 * 64 * 2);
  bf16*  T1     = (bf16*)alloc(12ull * 1024 * 128 * 2);
  bf16*  T3     = (bf16*)alloc(4ull * 768 * 3072 * 2);
  {
    size_t used = (size_t)(p - overlayBase);
    size_t cp = (size_t)nsplit * 8388608;
    p = overlayBase + (used > cp ? used : cp);
  }
  float* Cpart  = (float*)overlayBase;       // aliases dead prep buffers
  // -- persistent region --
  bf16*  G_t    = (bf16*)alloc(12ull * 2048 * 128 * 2);
  bf16*  Ut     = (bf16*)alloc(4ull * 2048 * 256 * 2);
  bf16*  E1     = (bf16*)alloc(12ull * 2048 * 128 * 2);
  bf16*  probsT = (bf16*)alloc(4ull * 256 * 3072 * 2);
  bf16*  maskb  = (bf16*)alloc(2048ull * 2048 * 2);
  float* invln  = (float*)alloc(1024 * 4);
  float* t_hk   = (float*)alloc(768 * 4);
  float* wv     = (float*)alloc(768 * 4);
  float* c0     = (float*)alloc(2048 * 4);
  float* c1     = (float*)alloc(2048 * 4);
  bf16*  A_g    = (bf16*)alloc((size_t)1024 * KA * 2);
  bf16*  B_g    = (bf16*)alloc((size_t)2048 * KA * 2);

  // ---- prep ----
  k_invln<<<4, 256, 0, stream>>>(lns, invln);
  k_cast4<<<1536, 256, 0, stream>>>(enc_W, encWb, 393216);
  k_probsT<<<3072, 256, 0, stream>>>(probs, probsT);
  k_maskb<<<4096, 256, 0, stream>>>(cmask, maskb, 1048576);
  k_WO<<<4608, 256, 0, stream>>>(W_O, WOb);
  k_WVtT<<<dim3(4, 24, 12), 256, 0, stream>>>(W_V, WVt);
  k_WOt<<<dim3(2, 24, 12), 256, 0, stream>>>(W_O, W_Ot);
  k_updWtT<<<dim3(64, 24), 256, 0, stream>>>(updW, updWt);
  k_Xb<<<768, 256, 0, stream>>>(resid, invln, Xb);
  k_UtT<<<dim3(64, 8, 4), 256, 0, stream>>>(pruned, invln, Ut);
  k_bias_t<<<768, 256, 0, stream>>>(W_V, up_b, t_hk);
  k_bias_w<<<768, 256, 0, stream>>>(W_O, t_hk, wv);
  k_bias_c<<<2048, 256, 0, stream>>>(enc_W, enc_b, b_dec, wv, c0, c1);

  // Merged E1 + G_t (z = 24, bb selects the problem via pointer-diff strides):
  //   bb=0: E1[h][f][k]  = encWb[f,o] . WOb[h][k][o]
  //   bb=1: G_t[h][u][k] = updWt[u,i] . WVt[h][k][i]
  gemm_bt<<<dim3(1, 16, 24), 256, 0, stream>>>(
      encWb, WOb, E1, 2048, 128, 768,
      768, 768, 128, 12,
      (long)(updWt - encWb), 0,
      (long)(WVt - WOb), (long)128 * 768,
      (long)(G_t - E1), (long)2048 * 128,
      0, 0, nullptr, 0);

  // ---- init path: T1 -> T3 -> S (appended into A_g K-tail) ----
  // T1[h][bs][k128] = Xb[bs,i] . WVt[h][k][i]   M=1024 N=128 K=768 (z=h)
  gemm_bt<<<dim3(1, 8, 12), 256, 0, stream>>>(
      Xb, WVt, T1, 1024, 128, 768,
      768, 768, 128, 12,
      0, 0, 0, (long)128 * 768, 0, (long)1024 * 128,
      0, 0, nullptr, 0);

  // T3[b][o][h*256+s] = W_Ot[h][o][k] . T1[h][b*256+s][k]   M=768 N=256 K=64
  // z=(b,h) via batchH=12
  gemm_bt<<<dim3(2, 6, 48), 256, 0, stream>>>(
      W_Ot, T1, T3, 768, 256, 64,
      64, 128, 3072, 12,
      0, (long)768 * 64, (long)256 * 128, (long)1024 * 128, 2359296, 256,
      0, 0, nullptr, 0);

  // S[b][q][o] = probsT[b][q][hs] . T3[b][o][hs]  -> A_g[:, gs*2048 .. +768]
  // M=256 N=768 K=3072 (z=b)
  gemm_bt<<<dim3(6, 2, 4), 256, 0, stream>>>(
      probsT, T3, A_g + (long)gs * 2048, 256, 768, 3072,
      3072, 3072, KA, 1,
      786432, 0, 2359296, 0, 256 * KA, 0,
      0, 0, nullptr, 0);

  // B_g K-tail: enc_W columns (so S @ enc_W^T rides inside the final GEMM)
  k_append<<<768, 256, 0, stream>>>(encWb, B_g + (long)gs * 2048, KA);

  // ---- head-group loop (single iteration when gs==12) ----
  for (int g = 0; g < 12 / gs; g++) {
    // V_g: B_g[f][hh*2048+u] = maskb[f,u] * (E1_h[f,k] . G_t_h[u,k])  K=128
    gemm_bt<<<dim3(16, 16, gs), 256, 0, stream>>>(
        E1 + (long)g * gs * 2048 * 128, G_t + (long)g * gs * 2048 * 128, B_g,
        2048, 2048, 128,
        128, 128, KA, gs,
        0, (long)2048 * 128, 0, (long)2048 * 128, 0, 2048,
        1, 0, maskb, 2048);

    // PU_g: A_g[b*256+q][hh*2048+u] = probsT[b][q][(g*gs+hh)*256 + s] . Ut[b][u][s]
    // M=256 N=2048 K=256, z=(b,hh) via batchH=gs
    gemm_bt<<<dim3(16, 2, 4 * gs), 256, 0, stream>>>(
        probsT + (long)g * gs * 256, Ut, A_g,
        256, 2048, 256,
        3072, 256, KA, gs,
        786432, 256, (long)2048 * 256, 0, 256 * KA, 2048,
        0, 0, nullptr, 0);

    // Cpart (+)= A_g[bq,k] . B_g[f,k]  -- 256x256-tile supply-optimized kernel
    // g==0 includes the 768-col [S | enc_W] tail; g>0 only the gs*2048 cols.
    int Kthis = (g == 0) ? (int)KA : gs * 2048;
    int kc = ((Kthis / nsplit + 63) / 64) * 64;
    gemm_fp2<<<dim3(8, 4, nsplit), 512, 0, stream>>>(
        A_g, B_g, Cpart,
        1024, 2048, Kthis,
        KA, KA, 2048,
        (g == 0) ? 2 : 3, kc);
  }

  // out[b,q,f] = fp32( sum_z Cpart + c0[f] + c1[f]*invln[bq] )
  k_out<<<2048, 256, 0, stream>>>(Cpart, c0, c1, invln, out, nsplit);
}

// Round 5
// 493.104 us; speedup vs baseline: 1.2157x; 1.0054x over previous
//
#include <hip/hip_runtime.h>
#include <hip/hip_bf16.h>
#include <stdint.h>

typedef __bf16 bf16;
typedef __bf16 bf16x8 __attribute__((ext_vector_type(8)));
typedef __bf16 bf16x4 __attribute__((ext_vector_type(4)));
typedef float f32x4 __attribute__((ext_vector_type(4)));

#define AS1 __attribute__((address_space(1)))
#define AS3 __attribute__((address_space(3)))

// B=4, S=256, H=12, DH=64(pad 128), D=768, FD=2048, FU=2048
// R24 (this round): final GEMM FETCH=253MB vs 156MB unique (97MB L2 refetch)
// and at 2x speed it would hit the 6.3TB/s HBM ceiling -> locality, not
// schedule, is the binding constraint. Old swizzle permuted (x,y) per-z so
// every XCD L2 mixed all 8 K-slabs (156MB live >> 4MiB). New mapping:
// z_work = flat_id % nz (flat_id%8 = XCD under round-robin dispatch) ->
// each XCD owns ONE z-slab; its 32 blocks walk K in ~lockstep with a
// ~384KB hot window << 4MiB L2 -> each HBM byte fetched once.

__device__ __forceinline__ void gld16(const bf16* g, bf16* l) {
  __builtin_amdgcn_global_load_lds((AS1 void*)g, (AS3 void*)l, 16, 0, 0);
}

__global__ void k_sentinel(float* __restrict__ out) {
  int i = blockIdx.x * 256 + threadIdx.x;
  if (i < 2097152) out[i] = 1048576.0f;
}

// ---------------- prep kernels ----------------

__global__ void k_invln(const float* __restrict__ ln, float* __restrict__ invln) {
  int i = blockIdx.x * 256 + threadIdx.x;
  if (i < 1024) invln[i] = 1.0f / ln[i];
}

// vectorized fp32 -> bf16 cast, n4 = n/4
__global__ void k_cast4(const float* __restrict__ s, bf16* __restrict__ d, int n4) {
  int i = blockIdx.x * 256 + threadIdx.x;
  if (i < n4) {
    float4 v = *(const float4*)(s + (long)i * 4);
    bf16x4 o;
    o[0] = (bf16)v.x; o[1] = (bf16)v.y; o[2] = (bf16)v.z; o[3] = (bf16)v.w;
    *(bf16x4*)(d + (long)i * 4) = o;
  }
}

// int32 0/1 mask -> bf16, n4 = n/4
__global__ void k_maskb(const int* __restrict__ m, bf16* __restrict__ d, int n4) {
  int i = blockIdx.x * 256 + threadIdx.x;
  if (i < n4) {
    int4 v = *(const int4*)(m + (long)i * 4);
    bf16x4 o;
    o[0] = (bf16)(float)v.x; o[1] = (bf16)(float)v.y;
    o[2] = (bf16)(float)v.z; o[3] = (bf16)(float)v.w;
    *(bf16x4*)(d + (long)i * 4) = o;
  }
}

// probsT[b][q][h*256+s] = bf16(probs[b,h,q,s])   (contiguous in s both sides)
__global__ void k_probsT(const float* __restrict__ probs, bf16* __restrict__ pT) {
  int i = blockIdx.x * 256 + threadIdx.x;   // 786432 vec4s
  if (i < 786432) {
    long idx = (long)i * 4;
    int s  = (int)(idx & 255);
    int q  = (int)((idx >> 8) & 255);
    int hb = (int)(idx >> 16);
    int h = hb % 12, b = hb / 12;
    float4 v = *(const float4*)(probs + idx);
    bf16x4 o;
    o[0] = (bf16)v.x; o[1] = (bf16)v.y; o[2] = (bf16)v.z; o[3] = (bf16)v.w;
    *(bf16x4*)(pT + (long)b * 786432 + (long)q * 3072 + h * 256 + s) = o;
  }
}

__global__ void k_WO(const float* __restrict__ W_O, bf16* __restrict__ WOb) {
  int i = blockIdx.x * 256 + threadIdx.x;           // 12*128*768
  int o = i % 768, r = (i / 768) & 127, h = i / (768 * 128);
  WOb[i] = (r < 64) ? (bf16)W_O[(long)(h * 64 + r) * 768 + o] : (bf16)0.0f;
}

// WVt[h][k<128][i<768] = W_V[h,i,k]  (tiled transpose, zero-pad k>=64)
__global__ void k_WVtT(const float* __restrict__ wv, bf16* __restrict__ WVt) {
  __shared__ float tile[32][33];
  int h = blockIdx.z;                 // 12
  int k0 = blockIdx.x * 32;           // 0..96
  int i0 = blockIdx.y * 32;           // 24 tiles
  int lane = threadIdx.x & 31, rg = threadIdx.x >> 5;
  if (k0 < 64) {
    for (int r = rg; r < 32; r += 8)
      tile[r][lane] = wv[((long)(h * 768 + i0 + r)) * 64 + k0 + lane];
    __syncthreads();
    for (int r = rg; r < 32; r += 8)
      WVt[((long)h * 128 + k0 + r) * 768 + i0 + lane] = (bf16)tile[lane][r];
  } else {
    for (int r = rg; r < 32; r += 8)
      WVt[((long)h * 128 + k0 + r) * 768 + i0 + lane] = (bf16)0.0f;
  }
}

// W_Ot[h][o][k64] = W_O[h,k,o]  (tiled transpose)
__global__ void k_WOt(const float* __restrict__ wo, bf16* __restrict__ W_Ot) {
  __shared__ float tile[32][33];
  int h = blockIdx.z;                 // 12
  int k0 = blockIdx.x * 32;           // 0..32
  int o0 = blockIdx.y * 32;           // 24 tiles
  int lane = threadIdx.x & 31, rg = threadIdx.x >> 5;
  for (int r = rg; r < 32; r += 8)
    tile[r][lane] = wo[((long)(h * 64 + k0 + r)) * 768 + o0 + lane];
  __syncthreads();
  for (int r = rg; r < 32; r += 8)
    W_Ot[((long)(h * 768 + o0 + r)) * 64 + k0 + lane] = (bf16)tile[lane][r];
}

// updWt[u][i] = up_dec_W[i][u]  (tiled transpose)
__global__ void k_updWtT(const float* __restrict__ u, bf16* __restrict__ d) {
  __shared__ float tile[32][33];
  int u0 = blockIdx.x * 32;           // 64 tiles
  int i0 = blockIdx.y * 32;           // 24 tiles
  int lane = threadIdx.x & 31, rg = threadIdx.x >> 5;
  for (int r = rg; r < 32; r += 8)
    tile[r][lane] = u[((long)(i0 + r)) * 2048 + u0 + lane];
  __syncthreads();
  for (int r = rg; r < 32; r += 8)
    d[((long)(u0 + r)) * 768 + i0 + lane] = (bf16)tile[lane][r];
}

// Xb[b*256+s][d] = resid[b,s,d] * invln (row-major bf16, no transpose)
__global__ void k_Xb(const float* __restrict__ resid, const float* __restrict__ invln,
                     bf16* __restrict__ Xb) {
  int i = blockIdx.x * 256 + threadIdx.x;   // 196608 vec4s
  if (i < 196608) {
    long idx = (long)i * 4;
    float il = invln[idx / 768];            // 4|768 so chunk never straddles rows
    float4 v = *(const float4*)(resid + idx);
    bf16x4 o;
    o[0] = (bf16)(v.x * il); o[1] = (bf16)(v.y * il);
    o[2] = (bf16)(v.z * il); o[3] = (bf16)(v.w * il);
    *(bf16x4*)(Xb + idx) = o;
  }
}

// Ut[b][u][s] = pruned[b,s,u] * invln  (tiled transpose)
__global__ void k_UtT(const float* __restrict__ pr, const float* __restrict__ invln,
                      bf16* __restrict__ Ut) {
  __shared__ float tile[32][33];
  int b = blockIdx.z, u0 = blockIdx.x * 32, s0 = blockIdx.y * 32;  // (64, 8, 4)
  int lane = threadIdx.x & 31, rg = threadIdx.x >> 5;
  for (int r = rg; r < 32; r += 8) {
    int s = s0 + r;
    tile[r][lane] = pr[((long)(b * 256 + s)) * 2048 + u0 + lane] * invln[b * 256 + s];
  }
  __syncthreads();
  for (int r = rg; r < 32; r += 8)
    Ut[((long)b * 2048 + u0 + r) * 256 + s0 + lane] = (bf16)tile[lane][r];
}

// append enc_W (bf16) as the 768-column K-tail of B_g
__global__ void k_append(const bf16* __restrict__ encWb, bf16* __restrict__ Bt, long ldb) {
  int i = blockIdx.x * 256 + threadIdx.x;   // 196608 vec8s
  if (i < 196608) {
    long idx = (long)i * 8;
    int f = (int)(idx / 768), d = (int)(idx % 768);
    *(bf16x8*)(Bt + (long)f * ldb + d) = *(const bf16x8*)(encWb + idx);
  }
}

// ---------------- bias chain (fp32, block-parallel) ----------------

__device__ __forceinline__ float blk_reduce(float s) {
  __shared__ float red[256];
  red[threadIdx.x] = s; __syncthreads();
  for (int o = 128; o > 0; o >>= 1) {
    if ((int)threadIdx.x < o) red[threadIdx.x] += red[threadIdx.x + o];
    __syncthreads();
  }
  float r = red[0]; __syncthreads();
  return r;
}

__global__ void k_bias_t(const float* __restrict__ W_V, const float* __restrict__ up_b,
                         float* __restrict__ t_hk) {
  int j = blockIdx.x, h = j >> 6, k = j & 63;
  float s = 0.f;
  for (int m = threadIdx.x; m < 768; m += 256)
    s += W_V[((long)(h * 768 + m)) * 64 + k] * up_b[m];
  float r = blk_reduce(s);
  if (threadIdx.x == 0) t_hk[j] = r;
}

__global__ void k_bias_w(const float* __restrict__ W_O, const float* __restrict__ t_hk,
                         float* __restrict__ w) {
  int d = blockIdx.x;
  float s = 0.f;
  for (int j = threadIdx.x; j < 768; j += 256)
    s += W_O[(long)j * 768 + d] * t_hk[j];
  float r = blk_reduce(s);
  if (threadIdx.x == 0) w[d] = r;
}

__global__ void k_bias_c(const float* __restrict__ enc_W, const float* __restrict__ enc_b,
                         const float* __restrict__ b_dec, const float* __restrict__ w,
                         float* __restrict__ c0, float* __restrict__ c1) {
  int f = blockIdx.x;
  float s0 = 0.f, s1 = 0.f;
  for (int d = threadIdx.x; d < 768; d += 256) {
    float e = enc_W[(long)f * 768 + d];
    s0 += e * b_dec[d];
    s1 += e * w[d];
  }
  float r0 = blk_reduce(s0);
  float r1 = blk_reduce(s1);
  if (threadIdx.x == 0) { c0[f] = enc_b[f] - r0; c1[f] = r1; }
}

// ---------------- GEMM (BT form: C[m,n] = sum_k A[m,k]*B[n,k]) ----------------
// BK=64, XOR-swizzled staging. K (and kChunk) must be multiples of 64.
// mode 0: bf16 store; mode 1: *= bf16 mask, bf16 store;
// mode 2: split-K fp32 overwrite; mode 3: split-K fp32 read-accumulate
__global__ __launch_bounds__(256)
void gemm_bt(const bf16* __restrict__ A, const bf16* __restrict__ B, void* __restrict__ Cv,
             int M, int N, int K,
             long lda, long ldb, long ldc,
             int batchH,
             long sa_b, long sa_h, long sb_b, long sb_h, long sc_b, long sc_h,
             int mode, int kChunk,
             const bf16* __restrict__ mask, long mask_ld)
{
  __shared__ __align__(16) bf16 Asm[128 * 64];
  __shared__ __align__(16) bf16 Bsm[128 * 64];

  const int t = threadIdx.x;

  // bijective XCD-aware remap of the (x,y) tile id (m204 formula)
  const int nbx = gridDim.x, nby = gridDim.y;
  const int nxy = nbx * nby;
  int orig = blockIdx.x + nbx * blockIdx.y;
  int qq = nxy >> 3, rr = nxy & 7;
  int xcd = orig & 7, lid = orig >> 3;
  int swz = (xcd < rr) ? (xcd * (qq + 1) + lid)
                       : (rr * (qq + 1) + (xcd - rr) * qq + lid);
  const int m0 = (swz % nby) * 128;
  const int n0 = (swz / nby) * 128;

  long aoff, boff, coff;
  int k0, k1;
  if (mode >= 2) {
    int z = blockIdx.z;
    aoff = 0; boff = 0;
    coff = (long)z * (long)M * ldc;
    k0 = z * kChunk; k1 = k0 + kChunk; if (k1 > K) k1 = K;
  } else {
    int z = blockIdx.z;
    int bb = z / batchH, hh = z - bb * batchH;
    aoff = (long)bb * sa_b + (long)hh * sa_h;
    boff = (long)bb * sb_b + (long)hh * sb_h;
    coff = (long)bb * sc_b + (long)hh * sc_h;
    k0 = 0; k1 = K;
  }

  const bf16* Ab = A + aoff + (long)m0 * lda;
  const bf16* Bb = B + boff + (long)n0 * ldb;

  const int r0 = t >> 3;           // 0..31 (staging row within 32-row group)
  const int g8 = t & 7;            // staging col-group (LDS slot)

  const int L = t & 63, w = t >> 6;
  const int wm = (w & 1) * 64, wn = (w >> 1) * 64;
  const int r16 = L & 15, q = L >> 4;

  f32x4 acc[4][4];
#pragma unroll
  for (int i = 0; i < 4; i++)
#pragma unroll
    for (int j = 0; j < 4; j++) acc[i][j] = (f32x4){0.f, 0.f, 0.f, 0.f};

  for (int kt = k0; kt < k1; kt += 64) {
#pragma unroll
    for (int j = 0; j < 4; j++) {
      int row = j * 32 + r0;
      int sc = ((g8 ^ (row & 7)) << 3);      // source col swizzle
      gld16(Ab + (long)row * lda + (kt + sc), &Asm[j * 2048 + t * 8]);
      gld16(Bb + (long)row * ldb + (kt + sc), &Bsm[j * 2048 + t * 8]);
    }
    __syncthreads();

#pragma unroll
    for (int h2 = 0; h2 < 2; h2++) {
      bf16x8 af[4], bfr[4];
#pragma unroll
      for (int i = 0; i < 4; i++) {
        int ra = wm + i * 16 + r16;
        af[i]  = *(const bf16x8*)&Asm[ra * 64 + ((((h2 << 2) + q) ^ (ra & 7)) << 3)];
        int rb = wn + i * 16 + r16;
        bfr[i] = *(const bf16x8*)&Bsm[rb * 64 + ((((h2 << 2) + q) ^ (rb & 7)) << 3)];
      }
#pragma unroll
      for (int mi = 0; mi < 4; mi++)
#pragma unroll
        for (int ni = 0; ni < 4; ni++)
          acc[mi][ni] = __builtin_amdgcn_mfma_f32_16x16x32_bf16(af[mi], bfr[ni], acc[mi][ni], 0, 0, 0);
    }
    __syncthreads();
  }

  if (mode >= 2) {
    float* C = (float*)Cv;
#pragma unroll
    for (int mi = 0; mi < 4; mi++)
#pragma unroll
      for (int ni = 0; ni < 4; ni++)
#pragma unroll
        for (int r = 0; r < 4; r++) {
          int gm = m0 + wm + mi * 16 + q * 4 + r;
          int gn = n0 + wn + ni * 16 + r16;
          long idx = coff + (long)gm * ldc + gn;
          float v = acc[mi][ni][r];
          if (mode == 3) v += C[idx];
          C[idx] = v;
        }
  } else {
    bf16* C = (bf16*)Cv;
#pragma unroll
    for (int mi = 0; mi < 4; mi++)
#pragma unroll
      for (int ni = 0; ni < 4; ni++)
#pragma unroll
        for (int r = 0; r < 4; r++) {
          int gm = m0 + wm + mi * 16 + q * 4 + r;
          int gn = n0 + wn + ni * 16 + r16;
          float v = acc[mi][ni][r];
          if (mode == 1) v *= (float)mask[(long)gm * mask_ld + gn];
          C[coff + (long)gm * ldc + gn] = (bf16)v;
        }
  }
}

// ------------- 256x256-tile split-K GEMM (final GEMM only) -------------------
// C[m,n] (+)= sum_k A[m,k]*B[n,k], fp32 C. 512 threads = 8 waves (2M x 4N),
// per-wave 128x64 output. BK=64. 2 LDS buffers (128 KiB), depth-1 prefetch,
// counted vmcnt(8) (0 only at epilogue), 2 barriers per K-step.
// Work remap: z_slab = flat_id % nz (flat_id%8 = XCD under round-robin
// dispatch) -> each XCD owns one K-slab; 32 blocks/XCD walk K in ~lockstep,
// hot window ~384KB << 4MiB L2 -> each HBM byte fetched once.
// K, kChunk multiples of 64. mode 2 = overwrite, 3 = read-accumulate.
__global__ __launch_bounds__(512, 2)
void gemm_fp2(const bf16* __restrict__ A, const bf16* __restrict__ B,
              float* __restrict__ C,
              int M, int N, int K, long lda, long ldb, long ldc,
              int mode, int kChunk)
{
  __shared__ __align__(16) bf16 SM[2][2][16384];   // [buf][A|B][256*64]

  const int t = threadIdx.x;

  const int nz = gridDim.z;
  int fid = blockIdx.x + gridDim.x * (blockIdx.y + gridDim.y * blockIdx.z);
  const int z  = fid % nz;                 // K-slab, constant per XCD when nz=8
  const int t2 = fid / nz;                 // 0..31 (m,n)-tile within the slab
  const int m0 = (t2 >> 3) * 256;          // 4 m-tiles
  const int n0 = (t2 & 7) * 256;           // 8 n-tiles

  const long coff = (long)z * (long)M * ldc;
  int k0 = z * kChunk, k1 = k0 + kChunk; if (k1 > K) k1 = K;
  const int NT = (k1 > k0) ? (k1 - k0) >> 6 : 0;

  const bf16* Ab = A + (long)m0 * lda + k0;
  const bf16* Bb = B + (long)n0 * ldb + k0;

  const int sr = t >> 3;           // 0..63 staging row within 64-row group
  const int g8 = t & 7;            // staging col-group (LDS slot)

  const int L = t & 63, w = t >> 6;          // 8 waves
  const int wm = (w & 1) * 128;              // 2 waves over M (256)
  const int wn = (w >> 1) * 64;              // 4 waves over N (256)
  const int r16 = L & 15, q = L >> 4;

  f32x4 acc[8][4];
#pragma unroll
  for (int i = 0; i < 8; i++)
#pragma unroll
    for (int j = 0; j < 4; j++) acc[i][j] = (f32x4){0.f, 0.f, 0.f, 0.f};

  // stage K-tile tt into buffer buf: 8 gld16 per thread (4 A rounds, 4 B)
  auto stage = [&](int tt, int buf) {
    const bf16* Ap = Ab + (long)tt * 64;
    const bf16* Bp = Bb + (long)tt * 64;
#pragma unroll
    for (int j = 0; j < 4; j++) {
      int row = j * 64 + sr;
      int sc = ((g8 ^ (row & 7)) << 3);
      gld16(Ap + (long)row * lda + sc, &SM[buf][0][j * 4096 + t * 8]);
    }
#pragma unroll
    for (int j = 0; j < 4; j++) {
      int row = j * 64 + sr;
      int sc = ((g8 ^ (row & 7)) << 3);
      gld16(Bp + (long)row * ldb + sc, &SM[buf][1][j * 4096 + t * 8]);
    }
  };

  if (NT >= 1) stage(0, 0);

  for (int tt = 0; tt < NT; tt++) {
    if (tt + 1 < NT) {
      stage(tt + 1, (tt + 1) & 1);           // prefetch next into other buffer
      asm volatile("s_waitcnt vmcnt(8)" ::: "memory");   // stage(tt) done
    } else {
      asm volatile("s_waitcnt vmcnt(0)" ::: "memory");   // epilogue drain
    }
    __builtin_amdgcn_s_barrier();            // buffer tt&1 ready for all waves

    const bf16* As = &SM[tt & 1][0][0];
    const bf16* Bs = &SM[tt & 1][1][0];
#pragma unroll
    for (int h2 = 0; h2 < 2; h2++) {
      bf16x8 af[8], bfr[4];
#pragma unroll
      for (int i = 0; i < 8; i++) {
        int ra = wm + i * 16 + r16;
        af[i]  = *(const bf16x8*)&As[ra * 64 + ((((h2 << 2) + q) ^ (ra & 7)) << 3)];
      }
#pragma unroll
      for (int i = 0; i < 4; i++) {
        int rb = wn + i * 16 + r16;
        bfr[i] = *(const bf16x8*)&Bs[rb * 64 + ((((h2 << 2) + q) ^ (rb & 7)) << 3)];
      }
#pragma unroll
      for (int mi = 0; mi < 8; mi++)
#pragma unroll
        for (int ni = 0; ni < 4; ni++)
          acc[mi][ni] = __builtin_amdgcn_mfma_f32_16x16x32_bf16(af[mi], bfr[ni], acc[mi][ni], 0, 0, 0);
    }
    __builtin_amdgcn_s_barrier();            // all waves done reading buf tt&1
  }

#pragma unroll
  for (int mi = 0; mi < 8; mi++)
#pragma unroll
    for (int ni = 0; ni < 4; ni++)
#pragma unroll
      for (int r = 0; r < 4; r++) {
        int gm = m0 + wm + mi * 16 + q * 4 + r;
        int gn = n0 + wn + ni * 16 + r16;
        long idx = coff + (long)gm * ldc + gn;
        float v = acc[mi][ni][r];
        if (mode == 3) v += C[idx];
        C[idx] = v;
      }
}

// ---------------- final reduce + bias epilogue (fp32 out, float4) ------------
__global__ void k_out(const float* __restrict__ Cp, const float* __restrict__ c0,
                      const float* __restrict__ c1, const float* __restrict__ invln,
                      float* __restrict__ out, int nsplit) {
  int i4 = blockIdx.x * 256 + threadIdx.x;          // 524288
  long i = (long)i4 * 4;
  int n = (int)(i & 2047), m = (int)(i >> 11);
  float4 v = *(const float4*)(Cp + i);
  for (int z = 1; z < nsplit; z++) {
    float4 u = *(const float4*)(Cp + i + (long)z * 2097152);
    v.x += u.x; v.y += u.y; v.z += u.z; v.w += u.w;
  }
  float il = invln[m];
  float4 a = *(const float4*)(c0 + n);
  float4 b = *(const float4*)(c1 + n);
  v.x += a.x + b.x * il;
  v.y += a.y + b.y * il;
  v.z += a.z + b.z * il;
  v.w += a.w + b.w * il;
  *(float4*)(out + i) = v;
}

// ---------------- host ----------------

extern "C" void kernel_launch(void* const* d_in, const int* in_sizes, int n_in,
                              void* d_out, int out_size, void* d_ws, size_t ws_size,
                              hipStream_t stream) {
  (void)out_size;
  float* out = (float*)d_out;

  // ---- resolve inputs by size (order-agnostic) ----
  int iresid = -1, iln = -1, iprobs = -1, iencb = -1, ipruned = -1, imask = -1;
  int iwo = -1, iwv = -1, iencw = -1, iupdw = -1, ibdec = -1, iupb = -1;
  for (int i = 0; i < n_in; i++) {
    switch (in_sizes[i]) {
      case 786432:  iresid  = i; break;
      case 1024:    iln     = i; break;
      case 3145728: iprobs  = i; break;
      case 2048:    iencb   = i; break;
      case 2097152: ipruned = i; break;
      case 4194304: imask   = i; break;
      case 589824:  if (iwo   < 0) iwo   = i; else iwv   = i; break;
      case 1572864: if (iencw < 0) iencw = i; else iupdw = i; break;
      case 768:     if (ibdec < 0) ibdec = i; else iupb  = i; break;
      default: break;
    }
  }
  bool ok = n_in == 12 && iresid >= 0 && iln >= 0 && iprobs >= 0 && iencb >= 0 &&
            ipruned >= 0 && imask >= 0 && iwo >= 0 && iwv >= 0 && iencw >= 0 &&
            iupdw >= 0 && ibdec >= 0 && iupb >= 0;
  if (!ok) { k_sentinel<<<8192, 256, 0, stream>>>(out); return; }

  const float* resid = (const float*)d_in[iresid];
  const float* lns   = (const float*)d_in[iln];
  const float* probs = (const float*)d_in[iprobs];
  const float* W_O   = (const float*)d_in[iwo];
  const float* W_V   = (const float*)d_in[iwv];
  const float* enc_W = (const float*)d_in[iencw];
  const float* enc_b = (const float*)d_in[iencb];
  const float* b_dec = (const float*)d_in[ibdec];
  const float* updW  = (const float*)d_in[iupdw];
  const float* up_b  = (const float*)d_in[iupb];
  const float* pruned= (const float*)d_in[ipruned];
  const int*   cmask = (const int*)d_in[imask];

  // ---- workspace sizing ----
  auto pad = [](size_t b) -> size_t { return (b + 255) & ~(size_t)255; };
  // overlay prep buffers (ALL dead before the first final-GEMM dispatch):
  const size_t prepB = pad(2359296) + pad(2359296) + pad(3145728) + pad(1572864) +
                       pad(3145728) + pad(1179648) + pad(3145728) + pad(18874368);
  // persistent (live across the g-loop): G_t, Ut, E1, probsT, maskb + smalls
  const size_t persB = pad(6291456) + pad(4194304) + pad(6291456) + pad(6291456) +
                       pad(8388608) + pad(4096) + pad(3072) + pad(3072) +
                       pad(8192) + pad(8192);
  auto needB = [&](int g, int ns) -> size_t {
    size_t cp = (size_t)ns * 8388608;
    size_t ov = prepB > cp ? prepB : cp;
    long KA = (long)g * 2048 + 768;
    size_t ab = pad((size_t)1024 * KA * 2) + pad((size_t)2048 * KA * 2);
    return ov + persB + ab + (2ull << 20);   // 2MiB slack
  };
  // prefer gs=12 (one final GEMM) + nsplit=8 (grid (8,4,8)=256 blocks = 1/CU)
  const int cgs[14] = {12, 12, 12, 6, 6, 4, 3, 2, 2, 1, 1, 1, 1, 1};
  const int cns[14] = { 8,  4, 2, 8, 4, 4, 4, 4, 2, 8, 4, 2, 2, 1};
  int gs = 0, nsplit = 0;
  for (int ci = 0; ci < 14; ci++) {
    if (needB(cgs[ci], cns[ci]) <= ws_size) { gs = cgs[ci]; nsplit = cns[ci]; break; }
  }
  if (gs == 0) { gs = 1; nsplit = 1; }

  const long KA = (long)gs * 2048 + 768;     // A_g/B_g leading dim (K incl. tail)

  char* p = (char*)d_ws;
  auto alloc = [&](size_t bytes) -> char* {
    char* r = p; p += (bytes + 255) & ~(size_t)255; return r;
  };
  // -- overlay region: prep buffers, later reused as Cpart --
  char* overlayBase = p;
  bf16*  WOb    = (bf16*)alloc(12ull * 128 * 768 * 2);
  bf16*  WVt    = (bf16*)alloc(12ull * 128 * 768 * 2);
  bf16*  updWt  = (bf16*)alloc(2048ull * 768 * 2);
  bf16*  Xb     = (bf16*)alloc(1024ull * 768 * 2);
  bf16*  encWb  = (bf16*)alloc(2048ull * 768 * 2);
  bf16*  W_Ot   = (bf16*)alloc(12ull * 768 * 64 * 2);
  bf16*  T1     = (bf16*)alloc(12ull * 1024 * 128 * 2);
  bf16*  T3     = (bf16*)alloc(4ull * 768 * 3072 * 2);
  {
    size_t used = (size_t)(p - overlayBase);
    size_t cp = (size_t)nsplit * 8388608;
    p = overlayBase + (used > cp ? used : cp);
  }
  float* Cpart  = (float*)overlayBase;       // aliases dead prep buffers
  // -- persistent region --
  bf16*  G_t    = (bf16*)alloc(12ull * 2048 * 128 * 2);
  bf16*  Ut     = (bf16*)alloc(4ull * 2048 * 256 * 2);
  bf16*  E1     = (bf16*)alloc(12ull * 2048 * 128 * 2);
  bf16*  probsT = (bf16*)alloc(4ull * 256 * 3072 * 2);
  bf16*  maskb  = (bf16*)alloc(2048ull * 2048 * 2);
  float* invln  = (float*)alloc(1024 * 4);
  float* t_hk   = (float*)alloc(768 * 4);
  float* wv     = (float*)alloc(768 * 4);
  float* c0     = (float*)alloc(2048 * 4);
  float* c1     = (float*)alloc(2048 * 4);
  bf16*  A_g    = (bf16*)alloc((size_t)1024 * KA * 2);
  bf16*  B_g    = (bf16*)alloc((size_t)2048 * KA * 2);

  // ---- prep ----
  k_invln<<<4, 256, 0, stream>>>(lns, invln);
  k_cast4<<<1536, 256, 0, stream>>>(enc_W, encWb, 393216);
  k_probsT<<<3072, 256, 0, stream>>>(probs, probsT);
  k_maskb<<<4096, 256, 0, stream>>>(cmask, maskb, 1048576);
  k_WO<<<4608, 256, 0, stream>>>(W_O, WOb);
  k_WVtT<<<dim3(4, 24, 12), 256, 0, stream>>>(W_V, WVt);
  k_WOt<<<dim3(2, 24, 12), 256, 0, stream>>>(W_O, W_Ot);
  k_updWtT<<<dim3(64, 24), 256, 0, stream>>>(updW, updWt);
  k_Xb<<<768, 256, 0, stream>>>(resid, invln, Xb);
  k_UtT<<<dim3(64, 8, 4), 256, 0, stream>>>(pruned, invln, Ut);
  k_bias_t<<<768, 256, 0, stream>>>(W_V, up_b, t_hk);
  k_bias_w<<<768, 256, 0, stream>>>(W_O, t_hk, wv);
  k_bias_c<<<2048, 256, 0, stream>>>(enc_W, enc_b, b_dec, wv, c0, c1);

  // Merged E1 + G_t (z = 24, bb selects the problem via pointer-diff strides):
  //   bb=0: E1[h][f][k]  = encWb[f,o] . WOb[h][k][o]
  //   bb=1: G_t[h][u][k] = updWt[u,i] . WVt[h][k][i]
  gemm_bt<<<dim3(1, 16, 24), 256, 0, stream>>>(
      encWb, WOb, E1, 2048, 128, 768,
      768, 768, 128, 12,
      (long)(updWt - encWb), 0,
      (long)(WVt - WOb), (long)128 * 768,
      (long)(G_t - E1), (long)2048 * 128,
      0, 0, nullptr, 0);

  // ---- init path: T1 -> T3 -> S (appended into A_g K-tail) ----
  // T1[h][bs][k128] = Xb[bs,i] . WVt[h][k][i]   M=1024 N=128 K=768 (z=h)
  gemm_bt<<<dim3(1, 8, 12), 256, 0, stream>>>(
      Xb, WVt, T1, 1024, 128, 768,
      768, 768, 128, 12,
      0, 0, 0, (long)128 * 768, 0, (long)1024 * 128,
      0, 0, nullptr, 0);

  // T3[b][o][h*256+s] = W_Ot[h][o][k] . T1[h][b*256+s][k]   M=768 N=256 K=64
  // z=(b,h) via batchH=12
  gemm_bt<<<dim3(2, 6, 48), 256, 0, stream>>>(
      W_Ot, T1, T3, 768, 256, 64,
      64, 128, 3072, 12,
      0, (long)768 * 64, (long)256 * 128, (long)1024 * 128, 2359296, 256,
      0, 0, nullptr, 0);

  // S[b][q][o] = probsT[b][q][hs] . T3[b][o][hs]  -> A_g[:, gs*2048 .. +768]
  // M=256 N=768 K=3072 (z=b)
  gemm_bt<<<dim3(6, 2, 4), 256, 0, stream>>>(
      probsT, T3, A_g + (long)gs * 2048, 256, 768, 3072,
      3072, 3072, KA, 1,
      786432, 0, 2359296, 0, 256 * KA, 0,
      0, 0, nullptr, 0);

  // B_g K-tail: enc_W columns (so S @ enc_W^T rides inside the final GEMM)
  k_append<<<768, 256, 0, stream>>>(encWb, B_g + (long)gs * 2048, KA);

  // ---- head-group loop (single iteration when gs==12) ----
  for (int g = 0; g < 12 / gs; g++) {
    // V_g: B_g[f][hh*2048+u] = maskb[f,u] * (E1_h[f,k] . G_t_h[u,k])  K=128
    gemm_bt<<<dim3(16, 16, gs), 256, 0, stream>>>(
        E1 + (long)g * gs * 2048 * 128, G_t + (long)g * gs * 2048 * 128, B_g,
        2048, 2048, 128,
        128, 128, KA, gs,
        0, (long)2048 * 128, 0, (long)2048 * 128, 0, 2048,
        1, 0, maskb, 2048);

    // PU_g: A_g[b*256+q][hh*2048+u] = probsT[b][q][(g*gs+hh)*256 + s] . Ut[b][u][s]
    // M=256 N=2048 K=256, z=(b,hh) via batchH=gs
    gemm_bt<<<dim3(16, 2, 4 * gs), 256, 0, stream>>>(
        probsT + (long)g * gs * 256, Ut, A_g,
        256, 2048, 256,
        3072, 256, KA, gs,
        786432, 256, (long)2048 * 256, 0, 256 * KA, 2048,
        0, 0, nullptr, 0);

    // Cpart (+)= A_g[bq,k] . B_g[f,k]  -- 256x256-tile, z-per-XCD locality
    // g==0 includes the 768-col [S | enc_W] tail; g>0 only the gs*2048 cols.
    int Kthis = (g == 0) ? (int)KA : gs * 2048;
    int kc = ((Kthis / nsplit + 63) / 64) * 64;
    gemm_fp2<<<dim3(8, 4, nsplit), 512, 0, stream>>>(
        A_g, B_g, Cpart,
        1024, 2048, Kthis,
        KA, KA, 2048,
        (g == 0) ? 2 : 3, kc);
  }

  // out[b,q,f] = fp32( sum_z Cpart + c0[f] + c1[f]*invln[bq] )
  k_out<<<2048, 256, 0, stream>>>(Cpart, c0, c1, invln, out, nsplit);
}